// Round 8
// baseline (275.744 us; speedup 1.0000x reference)
//
#include <hip/hip_runtime.h>
#include <math.h>

// ---------------------------------------------------------------------------
// 2-layer GCN. R8:
//  - gemm1: LDS-staged x tile (coalesced float4 global loads, padded-129 LDS,
//    lane=row ds_read) + wave-uniform f-quarter (scalar W1). R7's gemm1 read
//    x at 16B/lane stride-512B (1/8 coalescing) -> 62us, VALUBusy 17%.
//  - CSR build collapsed: tmp is dst-bucket-binned, so csr keeps per-bucket
//    gaps (bucket b occupies [b*CAP, b*CAP+count)). One kernel does LDS hist
//    -> LDS scan -> row_start/degs/dinv -> LDS-cursor scatter. Replaces
//    hist2+dinv+scan1/2/3+scatterB (6 launches, 3 passes -> 1 launch, 1 pass).
//  - agg kernels read e1 = row_start[v] + degs[v]; gap garbage in csr is only
//    ever loaded (never indexed) by masked lanes.
// ---------------------------------------------------------------------------

#define CHUNK 8192        // edges per scatterA block
#define BSHIFT 9          // 512 nodes per bucket
#define BMASK 511
#define CAP 9216          // tmp/csr slots per bucket (mean 8192, +11 sigma)

__device__ __forceinline__ unsigned f2b(float f) {  // fp32 -> bf16 bits (RNE)
  unsigned u = __float_as_uint(f);
  return (u + 0x7FFF + ((u >> 16) & 1)) >> 16;
}

// init bucket cursors + zero h1s row n (the "zero row" for masked gathers)
__global__ void binit_kernel(int* __restrict__ gbcursor, int nbc,
                             unsigned* __restrict__ h1s, int n) {
  int b = blockIdx.x * 256 + threadIdx.x;
  if (b < nbc) gbcursor[b] = b * CAP;
  if (blockIdx.x == 0 && threadIdx.x < 32) h1s[(size_t)n * 32 + threadIdx.x] = 0u;
}

// Block multisplit: pass1 LDS bucket hist; one global atomic per (block,bucket)
// reserves a segment; pass2 places edges via LDS cursors. pack=(src<<9)|(dst&511).
__global__ __launch_bounds__(256) void scatterA_kernel(const int* __restrict__ src,
                                                       const int* __restrict__ dst,
                                                       int E, int nbc,
                                                       int* __restrict__ gbcursor,
                                                       int* __restrict__ tmp) {
  __shared__ int hist[256];
  __shared__ int segcur[256];
  int tid = threadIdx.x;
  int estart = blockIdx.x * CHUNK;
  int eend = min(E, estart + CHUNK);
  hist[tid] = 0;
  __syncthreads();
  for (int i = estart + tid; i < eend; i += 256)
    atomicAdd(&hist[dst[i] >> BSHIFT], 1);
  __syncthreads();
  if (tid < nbc) {
    int c = hist[tid];
    segcur[tid] = c ? atomicAdd(&gbcursor[tid], c) : 0;
  }
  __syncthreads();
  for (int i = estart + tid; i < eend; i += 256) {
    int d = dst[i];
    int b = d >> BSHIFT;
    int pos = atomicAdd(&segcur[b], 1);
    if (pos < (b + 1) * CAP)  // statistically impossible overflow guard
      tmp[pos] = (src[i] << BSHIFT) | (d & BMASK);
  }
}

// One block per bucket: LDS degree hist -> LDS 512-scan (256 thr, pair trick)
// -> row_start/degs/dinv -> LDS-cursor scatter into bucket-local csr region.
__global__ __launch_bounds__(256) void csrbuild_kernel(const int* __restrict__ tmp,
                                                       const int* __restrict__ gbcursor,
                                                       int n, int* __restrict__ row_start,
                                                       int* __restrict__ degs,
                                                       float* __restrict__ dinv,
                                                       int* __restrict__ csr) {
  __shared__ int nh[512];
  __shared__ int sp[256];
  __shared__ int lcur[512];
  int b = blockIdx.x, tid = threadIdx.x;
  int base = b * CAP;
  int count = min(gbcursor[b] - base, CAP);
  nh[tid] = 0; nh[tid + 256] = 0;
  __syncthreads();
  for (int i = tid; i < count; i += 256) atomicAdd(&nh[tmp[base + i] & BMASK], 1);
  __syncthreads();
  int d0 = nh[2 * tid], d1 = nh[2 * tid + 1];
  int s = d0 + d1;
  sp[tid] = s;
  __syncthreads();
  for (int off = 1; off < 256; off <<= 1) {
    int a = sp[tid];
    int bb = (tid >= off) ? sp[tid - off] : 0;
    __syncthreads();
    sp[tid] = a + bb;
    __syncthreads();
  }
  int pp = sp[tid] - s;  // exclusive pair prefix
  int e0a = base + pp;
  int e0b = e0a + d0;
  lcur[2 * tid] = e0a;
  lcur[2 * tid + 1] = e0b;
  int vb = b << BSHIFT;
  int va = vb + 2 * tid;
  if (va < n) {
    row_start[va] = e0a; degs[va] = d0;
    dinv[va] = rsqrtf((float)(d0 + 1));
  }
  if (va + 1 < n) {
    row_start[va + 1] = e0b; degs[va + 1] = d1;
    dinv[va + 1] = rsqrtf((float)(d1 + 1));
  }
  __syncthreads();
  for (int i = tid; i < count; i += 256) {
    int val = tmp[base + i];
    int pos = atomicAdd(&lcur[val & BMASK], 1);
    csr[pos] = val >> BSHIFT;
  }
}

// h1s[row] = bf16x2-packed dinv[row] * (x[row] @ W1).
// Block = 64 rows. Stage x tile into LDS with coalesced float4 loads
// (pad 129 -> lane=row ds_read is 2-way aliased = free). Wave w computes
// f-quarter [16w,16w+16) (readfirstlane -> scalar W1 s_loads). acc[16].
__global__ __launch_bounds__(256, 4) void gemm1_kernel(const float* __restrict__ x,
                                                       const float* __restrict__ W1,
                                                       const float* __restrict__ dinv,
                                                       unsigned* __restrict__ h1s, int n) {
  __shared__ float xs[64 * 129];
  int tid = threadIdx.x;
  int vb = blockIdx.x * 64;
  int nrows = min(64, n - vb);
  const float4* xg = (const float4*)(x + (size_t)vb * 128);
#pragma unroll
  for (int it = 0; it < 8; ++it) {
    int idx = it * 256 + tid;      // [0, 2048) float4 slots, 32 per row
    int r = idx >> 5;
    if (r < nrows) {
      float4 vv = xg[idx];
      int cc = (idx & 31) * 4;
      float* p = &xs[r * 129 + cc];
      p[0] = vv.x; p[1] = vv.y; p[2] = vv.z; p[3] = vv.w;
    }
  }
  __syncthreads();
  int lane = tid & 63;
  int fbase = __builtin_amdgcn_readfirstlane((tid >> 6) * 16);  // wave-uniform
  int row = vb + lane;
  const float* Wp = W1 + fbase;  // SGPR base -> s_load path
  float acc[16];
#pragma unroll
  for (int f = 0; f < 16; ++f) acc[f] = 0.f;
#pragma unroll 8
  for (int k = 0; k < 128; ++k) {
    float xv = xs[lane * 129 + k];
#pragma unroll
    for (int f = 0; f < 16; ++f) acc[f] = fmaf(xv, Wp[(size_t)k * 64 + f], acc[f]);
  }
  if (row < n) {
    float dv = dinv[row];
    unsigned u[8];
#pragma unroll
    for (int j = 0; j < 8; ++j)
      u[j] = (f2b(dv * acc[2 * j + 1]) << 16) | f2b(dv * acc[2 * j]);
    uint4* o4 = (uint4*)(h1s + (size_t)row * 32 + 2 * fbase / 4);
    o4[0] = make_uint4(u[0], u[1], u[2], u[3]);
    o4[1] = make_uint4(u[4], u[5], u[6], u[7]);
  }
}

struct f2 { float x, y; };
__device__ __forceinline__ void addu(f2& a, unsigned u) {
  a.x += __uint_as_float(u << 16);
  a.y += __uint_as_float(u & 0xFFFF0000u);
}

// Wave-per-node, uint4 gathers. lane: e=lane>>3 (edge slot), c=lane&7 (16B
// chunk = features 8c..8c+7). One wave-load = 8 edges' rows. Row n of h1s is
// zeros -> masked tail gathers are branch-free. Grid-stride over node groups.
__global__ __launch_bounds__(256) void agg1_kernel(const uint4* __restrict__ h1s4,
                                                   const float* __restrict__ dinv,
                                                   const int* __restrict__ row_start,
                                                   const int* __restrict__ degs,
                                                   const int* __restrict__ csr,
                                                   const float* __restrict__ b1,
                                                   const float* __restrict__ W2,
                                                   float* __restrict__ t, int n) {
  __shared__ float W2s[64 * 17];
  __shared__ float b1s[64];
  __shared__ float a_s[4][64];
  for (int i = threadIdx.x; i < 1024; i += 256)
    W2s[(i >> 4) * 17 + (i & 15)] = W2[i];
  if (threadIdx.x < 64) b1s[threadIdx.x] = b1[threadIdx.x];
  // zero t row n for agg2's masked gathers (tmp alias is dead by now)
  if (blockIdx.x == 0 && threadIdx.x < 16) t[(size_t)n * 16 + threadIdx.x] = 0.f;
  __syncthreads();

  int wave = threadIdx.x >> 6, lane = threadIdx.x & 63;
  int e = lane >> 3, c = lane & 7;
  int j = lane & 15, fb = (lane >> 4) << 4;

  for (int vbase = blockIdx.x * 4; vbase < n; vbase += gridDim.x * 4) {
    int v = vbase + wave;
    bool valid = (v < n);           // wave-uniform
    int e0 = 0, e1 = 0;
    float dv = 0.f;
    if (valid) { e0 = row_start[v]; e1 = e0 + degs[v]; dv = dinv[v]; }

    f2 a0[4], a1[4];
#pragma unroll
    for (int k = 0; k < 4; ++k) { a0[k] = {0.f, 0.f}; a1[k] = {0.f, 0.f}; }
    {  // self loop (e==0 lanes pull row v; others pull zero row)
      int s = (valid && e == 0) ? v : n;
      uint4 g = h1s4[(size_t)s * 8 + c];
      addu(a0[0], g.x); addu(a0[1], g.y); addu(a0[2], g.z); addu(a0[3], g.w);
    }
    int i = e0;
    while (i + 8 < e1) {  // first gather fully valid, second masked
      int i1 = i + 8 + e;
      int s0 = csr[i + e];
      int s1v = csr[i1];
      int s1 = (i1 < e1) ? s1v : n;
      uint4 g0 = h1s4[(size_t)s0 * 8 + c];
      uint4 g1 = h1s4[(size_t)s1 * 8 + c];
      addu(a0[0], g0.x); addu(a0[1], g0.y); addu(a0[2], g0.z); addu(a0[3], g0.w);
      addu(a1[0], g1.x); addu(a1[1], g1.y); addu(a1[2], g1.z); addu(a1[3], g1.w);
      i += 16;
    }
    if (i < e1) {  // masked tail gather
      int i0 = i + e;
      int sv = csr[i0];
      int s = (i0 < e1) ? sv : n;
      uint4 g = h1s4[(size_t)s * 8 + c];
      addu(a0[0], g.x); addu(a0[1], g.y); addu(a0[2], g.z); addu(a0[3], g.w);
    }
#pragma unroll
    for (int k = 0; k < 4; ++k) { a0[k].x += a1[k].x; a0[k].y += a1[k].y; }
#pragma unroll
    for (int m = 8; m <= 32; m <<= 1) {
#pragma unroll
      for (int k = 0; k < 4; ++k) {
        a0[k].x += __shfl_xor(a0[k].x, m, 64);
        a0[k].y += __shfl_xor(a0[k].y, m, 64);
      }
    }
    if (lane < 8) {  // c == lane; features 8c..8c+7
#pragma unroll
      for (int k = 0; k < 4; ++k) {
        float z0 = fmaf(dv, a0[k].x, b1s[8 * lane + 2 * k]);
        float z1 = fmaf(dv, a0[k].y, b1s[8 * lane + 2 * k + 1]);
        a_s[wave][8 * lane + 2 * k] = fmaxf(z0, 0.2f * z0);
        a_s[wave][8 * lane + 2 * k + 1] = fmaxf(z1, 0.2f * z1);
      }
    }
    __threadfence_block();
    float p = 0.f;
#pragma unroll
    for (int q = 0; q < 16; ++q)
      p = fmaf(a_s[wave][fb + q], W2s[(fb + q) * 17 + j], p);
    p += __shfl_xor(p, 16, 64);
    p += __shfl_xor(p, 32, 64);
    if (valid && lane < 16) t[(size_t)v * 16 + j] = dv * p;  // dinv folded
    __threadfence_block();  // order a_s reuse across grid-stride iterations
  }
}

// 16 lanes per node, float4 gathers: sub=lane&15, e=sub>>2, c=sub&3.
// One wave-load covers 16 edges (4 nodes x 4 edges). Row n of t is zeros.
__global__ __launch_bounds__(256) void agg2_kernel(const float4* __restrict__ t4,
                                                   const float* __restrict__ dinv,
                                                   const int* __restrict__ row_start,
                                                   const int* __restrict__ degs,
                                                   const int* __restrict__ csr,
                                                   const float* __restrict__ b2,
                                                   float* __restrict__ out, int n) {
  int idx = blockIdx.x * 256 + threadIdx.x;
  int v = idx >> 4;
  if (v >= n) return;
  int sub = threadIdx.x & 15;
  int e = sub >> 2, c = sub & 3;
  float dv = dinv[v];
  int e0 = row_start[v], e1 = e0 + degs[v];
  float4 A0 = make_float4(0.f, 0.f, 0.f, 0.f), A1 = A0;
  {
    int s = (e == 0) ? v : n;
    float4 g = t4[(size_t)s * 4 + c];
    A0.x += g.x; A0.y += g.y; A0.z += g.z; A0.w += g.w;
  }
  int i = e0;
  while (i + 4 < e1) {
    int i1 = i + 4 + e;
    int s0 = csr[i + e];
    int s1v = csr[i1];
    int s1 = (i1 < e1) ? s1v : n;
    float4 g0 = t4[(size_t)s0 * 4 + c];
    float4 g1 = t4[(size_t)s1 * 4 + c];
    A0.x += g0.x; A0.y += g0.y; A0.z += g0.z; A0.w += g0.w;
    A1.x += g1.x; A1.y += g1.y; A1.z += g1.z; A1.w += g1.w;
    i += 8;
  }
  if (i < e1) {
    int i0 = i + e;
    int sv = csr[i0];
    int s = (i0 < e1) ? sv : n;
    float4 g = t4[(size_t)s * 4 + c];
    A0.x += g.x; A0.y += g.y; A0.z += g.z; A0.w += g.w;
  }
  A0.x += A1.x; A0.y += A1.y; A0.z += A1.z; A0.w += A1.w;
#pragma unroll
  for (int m = 4; m <= 8; m <<= 1) {  // reduce across e-groups
    A0.x += __shfl_xor(A0.x, m, 64);
    A0.y += __shfl_xor(A0.y, m, 64);
    A0.z += __shfl_xor(A0.z, m, 64);
    A0.w += __shfl_xor(A0.w, m, 64);
  }
  float4 bb = ((const float4*)b2)[c];
  float4 z;
  z.x = fmaf(dv, A0.x, bb.x); z.y = fmaf(dv, A0.y, bb.y);
  z.z = fmaf(dv, A0.z, bb.z); z.w = fmaf(dv, A0.w, bb.w);
  float m1 = fmaxf(fmaxf(z.x, z.y), fmaxf(z.z, z.w));
  m1 = fmaxf(m1, __shfl_xor(m1, 1, 64));  // across c-groups
  m1 = fmaxf(m1, __shfl_xor(m1, 2, 64));
  float4 p;
  p.x = expf(z.x - m1); p.y = expf(z.y - m1);
  p.z = expf(z.z - m1); p.w = expf(z.w - m1);
  float s4 = (p.x + p.y) + (p.z + p.w);
  s4 += __shfl_xor(s4, 1, 64);
  s4 += __shfl_xor(s4, 2, 64);
  float lg = m1 + logf(s4);
  if (e == 0) {
    float4 r;
    r.x = z.x - lg; r.y = z.y - lg; r.z = z.z - lg; r.w = z.w - lg;
    ((float4*)out)[(size_t)v * 4 + c] = r;
  }
}

extern "C" void kernel_launch(void* const* d_in, const int* in_sizes, int n_in,
                              void* d_out, int out_size, void* d_ws, size_t ws_size,
                              hipStream_t stream) {
  const float* x = (const float*)d_in[0];
  const int* edge_index = (const int*)d_in[1];
  const float* W1 = (const float*)d_in[2];
  const float* b1 = (const float*)d_in[3];
  const float* W2 = (const float*)d_in[4];
  const float* b2 = (const float*)d_in[5];
  float* out = (float*)d_out;

  int N_ = in_sizes[0] / 128;
  int E_ = in_sizes[1] / 2;
  const int* src = edge_index;
  const int* dst = edge_index + E_;
  int NBc = (N_ + BMASK) >> BSHIFT;  // 196 buckets of 512 nodes (<= 256)

  char* ws = (char*)d_ws;
  size_t off = 0;
  auto take = [&](size_t bytes) {
    void* p = ws + off;
    off += (bytes + 255) & ~(size_t)255;
    return p;
  };
  unsigned* h1s = (unsigned*)take(((size_t)N_ + 1) * 32 * 4);  // +1 zero row
  // t ((N+1)*16*4) aliases tmp (NBc*CAP*4): tmp dead before agg1 writes t.
  size_t t_bytes = ((size_t)N_ + 1) * 16 * 4, tmp_bytes = (size_t)NBc * CAP * 4;
  void* t_union = take(t_bytes > tmp_bytes ? t_bytes : tmp_bytes);
  float* t = (float*)t_union;
  int* tmp = (int*)t_union;
  float* dinv = (float*)take((size_t)N_ * 4);
  int* degs = (int*)take((size_t)N_ * 4);
  int* row_start = (int*)take(((size_t)N_ + 1) * 4);
  int* csr = (int*)take(((size_t)NBc * CAP + 16) * 4);  // bucket-local + pad
  int* gbcursor = (int*)take((size_t)NBc * 4);
  (void)ws_size;

  binit_kernel<<<(NBc + 255) / 256, 256, 0, stream>>>(gbcursor, NBc, h1s, N_);
  scatterA_kernel<<<(E_ + CHUNK - 1) / CHUNK, 256, 0, stream>>>(src, dst, E_, NBc,
                                                                gbcursor, tmp);
  csrbuild_kernel<<<NBc, 256, 0, stream>>>(tmp, gbcursor, N_, row_start, degs,
                                           dinv, csr);
  gemm1_kernel<<<(N_ + 63) / 64, 256, 0, stream>>>(x, W1, dinv, h1s, N_);
  agg1_kernel<<<2048, 256, 0, stream>>>((const uint4*)h1s, dinv, row_start, degs,
                                        csr, b1, W2, t, N_);
  agg2_kernel<<<(N_ * 16 + 255) / 256, 256, 0, stream>>>((const float4*)t, dinv,
                                                         row_start, degs, csr,
                                                         b2, out, N_);
}

// Round 9
// 237.704 us; speedup vs baseline: 1.1600x; 1.1600x over previous
//
#include <hip/hip_runtime.h>
#include <math.h>

// ---------------------------------------------------------------------------
// 2-layer GCN. R9:
//  - gemm1 via MFMA (16x16x32 bf16). R7/R8 FMA versions were stuck at ~63us:
//    mixing ds_read/s_load on lgkmcnt serializes the k-loop (VALUBusy 15%).
//    Now: stage x-tile + W1^T as bf16 in LDS (stride 68 u32, 16B-aligned
//    frags), 4 waves x 16 rows x 16 MFMAs, dinv fold + bf16 pack epilogue.
//    C-layout: col=lane&15, row=quad*4+reg (HW-verified mapping).
//  - t stored packed bf16 (32B/row): agg1 packs via lane-pair shuffle; agg2
//    gathers uint4 = half row -> 8 edges per wave-load, traffic halved.
// ---------------------------------------------------------------------------

#define CHUNK 8192        // edges per scatterA block
#define BSHIFT 9          // 512 nodes per bucket
#define BMASK 511
#define CAP 9216          // tmp/csr slots per bucket (mean 8192, +11 sigma)

typedef __bf16 bf16x8 __attribute__((ext_vector_type(8)));
typedef float f32x4 __attribute__((ext_vector_type(4)));

__device__ __forceinline__ unsigned f2b(float f) {  // fp32 -> bf16 bits (RNE)
  unsigned u = __float_as_uint(f);
  return (u + 0x7FFF + ((u >> 16) & 1)) >> 16;
}

// init bucket cursors + zero h1s row n (the "zero row" for masked gathers)
__global__ void binit_kernel(int* __restrict__ gbcursor, int nbc,
                             unsigned* __restrict__ h1s, int n) {
  int b = blockIdx.x * 256 + threadIdx.x;
  if (b < nbc) gbcursor[b] = b * CAP;
  if (blockIdx.x == 0 && threadIdx.x < 32) h1s[(size_t)n * 32 + threadIdx.x] = 0u;
}

// Block multisplit: pass1 LDS bucket hist; one global atomic per (block,bucket)
// reserves a segment; pass2 places edges via LDS cursors. pack=(src<<9)|(dst&511).
__global__ __launch_bounds__(256) void scatterA_kernel(const int* __restrict__ src,
                                                       const int* __restrict__ dst,
                                                       int E, int nbc,
                                                       int* __restrict__ gbcursor,
                                                       int* __restrict__ tmp) {
  __shared__ int hist[256];
  __shared__ int segcur[256];
  int tid = threadIdx.x;
  int estart = blockIdx.x * CHUNK;
  int eend = min(E, estart + CHUNK);
  hist[tid] = 0;
  __syncthreads();
  for (int i = estart + tid; i < eend; i += 256)
    atomicAdd(&hist[dst[i] >> BSHIFT], 1);
  __syncthreads();
  if (tid < nbc) {
    int c = hist[tid];
    segcur[tid] = c ? atomicAdd(&gbcursor[tid], c) : 0;
  }
  __syncthreads();
  for (int i = estart + tid; i < eend; i += 256) {
    int d = dst[i];
    int b = d >> BSHIFT;
    int pos = atomicAdd(&segcur[b], 1);
    if (pos < (b + 1) * CAP)  // statistically impossible overflow guard
      tmp[pos] = (src[i] << BSHIFT) | (d & BMASK);
  }
}

// One block per bucket: LDS degree hist -> LDS 512-scan (256 thr, pair trick)
// -> row_start/degs/dinv -> LDS-cursor scatter into bucket-local csr region.
__global__ __launch_bounds__(256) void csrbuild_kernel(const int* __restrict__ tmp,
                                                       const int* __restrict__ gbcursor,
                                                       int n, int* __restrict__ row_start,
                                                       int* __restrict__ degs,
                                                       float* __restrict__ dinv,
                                                       int* __restrict__ csr) {
  __shared__ int nh[512];
  __shared__ int sp[256];
  __shared__ int lcur[512];
  int b = blockIdx.x, tid = threadIdx.x;
  int base = b * CAP;
  int count = min(gbcursor[b] - base, CAP);
  nh[tid] = 0; nh[tid + 256] = 0;
  __syncthreads();
  for (int i = tid; i < count; i += 256) atomicAdd(&nh[tmp[base + i] & BMASK], 1);
  __syncthreads();
  int d0 = nh[2 * tid], d1 = nh[2 * tid + 1];
  int s = d0 + d1;
  sp[tid] = s;
  __syncthreads();
  for (int off = 1; off < 256; off <<= 1) {
    int a = sp[tid];
    int bb = (tid >= off) ? sp[tid - off] : 0;
    __syncthreads();
    sp[tid] = a + bb;
    __syncthreads();
  }
  int pp = sp[tid] - s;  // exclusive pair prefix
  int e0a = base + pp;
  int e0b = e0a + d0;
  lcur[2 * tid] = e0a;
  lcur[2 * tid + 1] = e0b;
  int vb = b << BSHIFT;
  int va = vb + 2 * tid;
  if (va < n) {
    row_start[va] = e0a; degs[va] = d0;
    dinv[va] = rsqrtf((float)(d0 + 1));
  }
  if (va + 1 < n) {
    row_start[va + 1] = e0b; degs[va + 1] = d1;
    dinv[va + 1] = rsqrtf((float)(d1 + 1));
  }
  __syncthreads();
  for (int i = tid; i < count; i += 256) {
    int val = tmp[base + i];
    int pos = atomicAdd(&lcur[val & BMASK], 1);
    csr[pos] = val >> BSHIFT;
  }
}

// h1s[row] = bf16x2-packed dinv[row] * (x[row] @ W1), via MFMA.
// Block = 64 rows; LDS holds x-tile (64x128 bf16, stride 68 u32) and W1^T
// (64x128 bf16, same stride). Wave w: rows w*16..w*16+15; 4 ks x 4 nt MFMAs.
__global__ __launch_bounds__(256, 4) void gemm1_kernel(const float* __restrict__ x,
                                                       const float* __restrict__ W1,
                                                       const float* __restrict__ dinv,
                                                       unsigned* __restrict__ h1s, int n) {
  __shared__ unsigned lds_u[64 * 68 * 2];
  unsigned* xs = lds_u;
  unsigned* wt = lds_u + 64 * 68;
  int tid = threadIdx.x;
  int vb = blockIdx.x * 64;
  int nrows = min(64, n - vb);

  // stage x: coalesced float4 loads, pack to bf16x2
  const float4* xg = (const float4*)(x + (size_t)vb * 128);
#pragma unroll
  for (int it = 0; it < 8; ++it) {
    int idx = it * 256 + tid;
    int r = idx >> 5, c2 = idx & 31;
    float4 vv = make_float4(0.f, 0.f, 0.f, 0.f);
    if (r < nrows) vv = xg[idx];
    xs[r * 68 + c2 * 2] = (f2b(vv.y) << 16) | f2b(vv.x);
    xs[r * 68 + c2 * 2 + 1] = (f2b(vv.w) << 16) | f2b(vv.z);
  }
  // stage W1^T: wt16[n][k] bf16, stride 136 u16 (= 68 u32)
  unsigned short* wt16 = (unsigned short*)wt;
  const float4* wg = (const float4*)W1;
#pragma unroll
  for (int it = 0; it < 8; ++it) {
    int idx = it * 256 + tid;          // [0,2048): k = idx>>4, n0 = (idx&15)*4
    int k = idx >> 4, n0 = (idx & 15) * 4;
    float4 wv = wg[idx];
    wt16[(n0 + 0) * 136 + k] = (unsigned short)f2b(wv.x);
    wt16[(n0 + 1) * 136 + k] = (unsigned short)f2b(wv.y);
    wt16[(n0 + 2) * 136 + k] = (unsigned short)f2b(wv.z);
    wt16[(n0 + 3) * 136 + k] = (unsigned short)f2b(wv.w);
  }
  __syncthreads();

  int lane = tid & 63, wid = tid >> 6;
  int m16 = lane & 15, quad = lane >> 4;
  const unsigned* xp = xs + (wid * 16 + m16) * 68 + quad * 4;
  const unsigned* wp = wt + m16 * 68 + quad * 4;
  f32x4 acc[4] = {};
#pragma unroll
  for (int ks = 0; ks < 4; ++ks) {
    bf16x8 a = *(const bf16x8*)(xp + ks * 16);
#pragma unroll
    for (int nt = 0; nt < 4; ++nt) {
      bf16x8 b = *(const bf16x8*)(wp + nt * 16 * 68 + ks * 16);
      acc[nt] = __builtin_amdgcn_mfma_f32_16x16x32_bf16(a, b, acc[nt], 0, 0, 0);
    }
  }
  // epilogue: C[row = quad*4+reg][col = nt*16+m16]; fold dinv, pack bf16
  int rbase = vb + wid * 16 + quad * 4;
  float dvv[4];
#pragma unroll
  for (int reg = 0; reg < 4; ++reg) {
    int row = rbase + reg;
    dvv[reg] = (row < n) ? dinv[row] : 0.f;
  }
  unsigned short* h16 = (unsigned short*)h1s;
#pragma unroll
  for (int nt = 0; nt < 4; ++nt) {
    int col = nt * 16 + m16;
#pragma unroll
    for (int reg = 0; reg < 4; ++reg) {
      int row = rbase + reg;
      if (row < n)
        h16[(size_t)row * 64 + col] = (unsigned short)f2b(dvv[reg] * acc[nt][reg]);
    }
  }
}

struct f2 { float x, y; };
__device__ __forceinline__ void addu(f2& a, unsigned u) {
  a.x += __uint_as_float(u << 16);
  a.y += __uint_as_float(u & 0xFFFF0000u);
}

// Wave-per-node, uint4 gathers. lane: e=lane>>3 (edge slot), c=lane&7 (16B
// chunk = features 8c..8c+7). One wave-load = 8 edges' rows. Row n of h1s is
// zeros -> masked tail gathers are branch-free. Grid-stride over node groups.
// Epilogue: 64x16 linear, dinv fold, pack t as bf16x2 (8 u32 per node).
__global__ __launch_bounds__(256) void agg1_kernel(const uint4* __restrict__ h1s4,
                                                   const float* __restrict__ dinv,
                                                   const int* __restrict__ row_start,
                                                   const int* __restrict__ degs,
                                                   const int* __restrict__ csr,
                                                   const float* __restrict__ b1,
                                                   const float* __restrict__ W2,
                                                   unsigned* __restrict__ t, int n) {
  __shared__ float W2s[64 * 17];
  __shared__ float b1s[64];
  __shared__ float a_s[4][64];
  for (int i = threadIdx.x; i < 1024; i += 256)
    W2s[(i >> 4) * 17 + (i & 15)] = W2[i];
  if (threadIdx.x < 64) b1s[threadIdx.x] = b1[threadIdx.x];
  // zero t row n for agg2's masked gathers (tmp alias is dead by now)
  if (blockIdx.x == 0 && threadIdx.x < 8) t[(size_t)n * 8 + threadIdx.x] = 0u;
  __syncthreads();

  int wave = threadIdx.x >> 6, lane = threadIdx.x & 63;
  int e = lane >> 3, c = lane & 7;
  int j = lane & 15, fb = (lane >> 4) << 4;

  for (int vbase = blockIdx.x * 4; vbase < n; vbase += gridDim.x * 4) {
    int v = vbase + wave;
    bool valid = (v < n);           // wave-uniform
    int e0 = 0, e1 = 0;
    float dv = 0.f;
    if (valid) { e0 = row_start[v]; e1 = e0 + degs[v]; dv = dinv[v]; }

    f2 a0[4], a1[4];
#pragma unroll
    for (int k = 0; k < 4; ++k) { a0[k] = {0.f, 0.f}; a1[k] = {0.f, 0.f}; }
    {  // self loop (e==0 lanes pull row v; others pull zero row)
      int s = (valid && e == 0) ? v : n;
      uint4 g = h1s4[(size_t)s * 8 + c];
      addu(a0[0], g.x); addu(a0[1], g.y); addu(a0[2], g.z); addu(a0[3], g.w);
    }
    int i = e0;
    while (i + 8 < e1) {  // first gather fully valid, second masked
      int i1 = i + 8 + e;
      int s0 = csr[i + e];
      int s1v = csr[i1];
      int s1 = (i1 < e1) ? s1v : n;
      uint4 g0 = h1s4[(size_t)s0 * 8 + c];
      uint4 g1 = h1s4[(size_t)s1 * 8 + c];
      addu(a0[0], g0.x); addu(a0[1], g0.y); addu(a0[2], g0.z); addu(a0[3], g0.w);
      addu(a1[0], g1.x); addu(a1[1], g1.y); addu(a1[2], g1.z); addu(a1[3], g1.w);
      i += 16;
    }
    if (i < e1) {  // masked tail gather
      int i0 = i + e;
      int sv = csr[i0];
      int s = (i0 < e1) ? sv : n;
      uint4 g = h1s4[(size_t)s * 8 + c];
      addu(a0[0], g.x); addu(a0[1], g.y); addu(a0[2], g.z); addu(a0[3], g.w);
    }
#pragma unroll
    for (int k = 0; k < 4; ++k) { a0[k].x += a1[k].x; a0[k].y += a1[k].y; }
#pragma unroll
    for (int m = 8; m <= 32; m <<= 1) {
#pragma unroll
      for (int k = 0; k < 4; ++k) {
        a0[k].x += __shfl_xor(a0[k].x, m, 64);
        a0[k].y += __shfl_xor(a0[k].y, m, 64);
      }
    }
    if (lane < 8) {  // c == lane; features 8c..8c+7
#pragma unroll
      for (int k = 0; k < 4; ++k) {
        float z0 = fmaf(dv, a0[k].x, b1s[8 * lane + 2 * k]);
        float z1 = fmaf(dv, a0[k].y, b1s[8 * lane + 2 * k + 1]);
        a_s[wave][8 * lane + 2 * k] = fmaxf(z0, 0.2f * z0);
        a_s[wave][8 * lane + 2 * k + 1] = fmaxf(z1, 0.2f * z1);
      }
    }
    __threadfence_block();
    float p = 0.f;
#pragma unroll
    for (int q = 0; q < 16; ++q)
      p = fmaf(a_s[wave][fb + q], W2s[(fb + q) * 17 + j], p);
    p += __shfl_xor(p, 16, 64);
    p += __shfl_xor(p, 32, 64);
    // pack pairs: lane<16 holds feature j; even lanes write u32 (feat j, j+1)
    float pv = dv * p;
    float po = __shfl_xor(pv, 1, 64);
    if (valid && lane < 16 && !(lane & 1))
      t[(size_t)v * 8 + (lane >> 1)] = (f2b(po) << 16) | f2b(pv);
    __threadfence_block();  // order a_s reuse across grid-stride iterations
  }
}

// 16 lanes per node, bf16 t rows (32B). sub=lane&15: e=sub>>1 (8 edge slots),
// c=sub&1 (uint4 half = features 8c..8c+7). One wave-load = 8 edges x 4 nodes.
// Row n of t is zeros. log_softmax via 8-local + xor-1 lane reduce.
__global__ __launch_bounds__(256) void agg2_kernel(const uint4* __restrict__ t4,
                                                   const float* __restrict__ dinv,
                                                   const int* __restrict__ row_start,
                                                   const int* __restrict__ degs,
                                                   const int* __restrict__ csr,
                                                   const float* __restrict__ b2,
                                                   float* __restrict__ out, int n) {
  int idx = blockIdx.x * 256 + threadIdx.x;
  int v = idx >> 4;
  if (v >= n) return;
  int sub = threadIdx.x & 15;
  int e = sub >> 1, c = sub & 1;
  float dv = dinv[v];
  int e0 = row_start[v], e1 = e0 + degs[v];
  f2 A0[4], A1[4];
#pragma unroll
  for (int k = 0; k < 4; ++k) { A0[k] = {0.f, 0.f}; A1[k] = {0.f, 0.f}; }
  {  // self loop
    int s = (e == 0) ? v : n;
    uint4 g = t4[(size_t)s * 2 + c];
    addu(A0[0], g.x); addu(A0[1], g.y); addu(A0[2], g.z); addu(A0[3], g.w);
  }
  int i = e0;
  while (i + 8 < e1) {
    int i1 = i + 8 + e;
    int s0 = csr[i + e];
    int s1v = csr[i1];
    int s1 = (i1 < e1) ? s1v : n;
    uint4 g0 = t4[(size_t)s0 * 2 + c];
    uint4 g1 = t4[(size_t)s1 * 2 + c];
    addu(A0[0], g0.x); addu(A0[1], g0.y); addu(A0[2], g0.z); addu(A0[3], g0.w);
    addu(A1[0], g1.x); addu(A1[1], g1.y); addu(A1[2], g1.z); addu(A1[3], g1.w);
    i += 16;
  }
  if (i < e1) {
    int i0 = i + e;
    int sv = csr[i0];
    int s = (i0 < e1) ? sv : n;
    uint4 g = t4[(size_t)s * 2 + c];
    addu(A0[0], g.x); addu(A0[1], g.y); addu(A0[2], g.z); addu(A0[3], g.w);
  }
#pragma unroll
  for (int k = 0; k < 4; ++k) { A0[k].x += A1[k].x; A0[k].y += A1[k].y; }
#pragma unroll
  for (int m = 2; m <= 8; m <<= 1) {  // reduce across e-groups (sub bits 1..3)
#pragma unroll
    for (int k = 0; k < 4; ++k) {
      A0[k].x += __shfl_xor(A0[k].x, m, 64);
      A0[k].y += __shfl_xor(A0[k].y, m, 64);
    }
  }
  // z for features 8c..8c+7
  float4 bb0 = ((const float4*)b2)[c * 2];
  float4 bb1 = ((const float4*)b2)[c * 2 + 1];
  float z[8];
  z[0] = fmaf(dv, A0[0].x, bb0.x); z[1] = fmaf(dv, A0[0].y, bb0.y);
  z[2] = fmaf(dv, A0[1].x, bb0.z); z[3] = fmaf(dv, A0[1].y, bb0.w);
  z[4] = fmaf(dv, A0[2].x, bb1.x); z[5] = fmaf(dv, A0[2].y, bb1.y);
  z[6] = fmaf(dv, A0[3].x, bb1.z); z[7] = fmaf(dv, A0[3].y, bb1.w);
  float mx = z[0];
#pragma unroll
  for (int q = 1; q < 8; ++q) mx = fmaxf(mx, z[q]);
  mx = fmaxf(mx, __shfl_xor(mx, 1, 64));  // combine c halves
  float ss = 0.f;
#pragma unroll
  for (int q = 0; q < 8; ++q) ss += expf(z[q] - mx);
  ss += __shfl_xor(ss, 1, 64);
  float lg = mx + logf(ss);
  if (e == 0) {
    float4 r0 = make_float4(z[0] - lg, z[1] - lg, z[2] - lg, z[3] - lg);
    float4 r1 = make_float4(z[4] - lg, z[5] - lg, z[6] - lg, z[7] - lg);
    float4* o = (float4*)out + (size_t)v * 4 + c * 2;
    o[0] = r0;
    o[1] = r1;
  }
}

extern "C" void kernel_launch(void* const* d_in, const int* in_sizes, int n_in,
                              void* d_out, int out_size, void* d_ws, size_t ws_size,
                              hipStream_t stream) {
  const float* x = (const float*)d_in[0];
  const int* edge_index = (const int*)d_in[1];
  const float* W1 = (const float*)d_in[2];
  const float* b1 = (const float*)d_in[3];
  const float* W2 = (const float*)d_in[4];
  const float* b2 = (const float*)d_in[5];
  float* out = (float*)d_out;

  int N_ = in_sizes[0] / 128;
  int E_ = in_sizes[1] / 2;
  const int* src = edge_index;
  const int* dst = edge_index + E_;
  int NBc = (N_ + BMASK) >> BSHIFT;  // 196 buckets of 512 nodes (<= 256)

  char* ws = (char*)d_ws;
  size_t off = 0;
  auto take = [&](size_t bytes) {
    void* p = ws + off;
    off += (bytes + 255) & ~(size_t)255;
    return p;
  };
  unsigned* h1s = (unsigned*)take(((size_t)N_ + 1) * 32 * 4);  // +1 zero row
  // t ((N+1)*8*4 bf16-packed) aliases tmp (NBc*CAP*4): tmp dead before agg1.
  size_t t_bytes = ((size_t)N_ + 1) * 8 * 4, tmp_bytes = (size_t)NBc * CAP * 4;
  void* t_union = take(t_bytes > tmp_bytes ? t_bytes : tmp_bytes);
  unsigned* t = (unsigned*)t_union;
  int* tmp = (int*)t_union;
  float* dinv = (float*)take((size_t)N_ * 4);
  int* degs = (int*)take((size_t)N_ * 4);
  int* row_start = (int*)take(((size_t)N_ + 1) * 4);
  int* csr = (int*)take(((size_t)NBc * CAP + 16) * 4);  // bucket-local + pad
  int* gbcursor = (int*)take((size_t)NBc * 4);
  (void)ws_size;

  binit_kernel<<<(NBc + 255) / 256, 256, 0, stream>>>(gbcursor, NBc, h1s, N_);
  scatterA_kernel<<<(E_ + CHUNK - 1) / CHUNK, 256, 0, stream>>>(src, dst, E_, NBc,
                                                                gbcursor, tmp);
  csrbuild_kernel<<<NBc, 256, 0, stream>>>(tmp, gbcursor, N_, row_start, degs,
                                           dinv, csr);
  gemm1_kernel<<<(N_ + 63) / 64, 256, 0, stream>>>(x, W1, dinv, h1s, N_);
  agg1_kernel<<<2048, 256, 0, stream>>>((const uint4*)h1s, dinv, row_start, degs,
                                        csr, b1, W2, t, N_);
  agg2_kernel<<<(N_ * 16 + 255) / 256, 256, 0, stream>>>((const uint4*)t, dinv,
                                                         row_start, degs, csr,
                                                         b2, out, N_);
}

// Round 10
// 227.658 us; speedup vs baseline: 1.2112x; 1.0441x over previous
//
#include <hip/hip_runtime.h>
#include <math.h>

// ---------------------------------------------------------------------------
// 2-layer GCN. R10: agg1 half-wave dual-node.
// R9's agg1 (63us) was outstanding-request-limited: ~3 gathers in flight/wave,
// VALUBusy 46%, 1.47TB/s (R6->R7 showed MLP still pays). Now lanes 0-31 serve
// node A, 32-63 node B: each gather instr covers 2 nodes -> ~2x requests in
// flight at UNCHANGED VGPR (lane owns one node). e-butterfly 3->2 levels.
// bf16 unpack drops the AND (low-mantissa noise << error budget).
// ---------------------------------------------------------------------------

#define CHUNK 8192        // edges per scatterA block
#define BSHIFT 9          // 512 nodes per bucket
#define BMASK 511
#define CAP 9216          // tmp/csr slots per bucket (mean 8192, +11 sigma)

typedef __bf16 bf16x8 __attribute__((ext_vector_type(8)));
typedef float f32x4 __attribute__((ext_vector_type(4)));

__device__ __forceinline__ unsigned f2b(float f) {  // fp32 -> bf16 bits (RNE)
  unsigned u = __float_as_uint(f);
  return (u + 0x7FFF + ((u >> 16) & 1)) >> 16;
}

// init bucket cursors + zero h1s row n (the "zero row" for masked gathers)
__global__ void binit_kernel(int* __restrict__ gbcursor, int nbc,
                             unsigned* __restrict__ h1s, int n) {
  int b = blockIdx.x * 256 + threadIdx.x;
  if (b < nbc) gbcursor[b] = b * CAP;
  if (blockIdx.x == 0 && threadIdx.x < 32) h1s[(size_t)n * 32 + threadIdx.x] = 0u;
}

// Block multisplit: pass1 LDS bucket hist; one global atomic per (block,bucket)
// reserves a segment; pass2 places edges via LDS cursors. pack=(src<<9)|(dst&511).
__global__ __launch_bounds__(256) void scatterA_kernel(const int* __restrict__ src,
                                                       const int* __restrict__ dst,
                                                       int E, int nbc,
                                                       int* __restrict__ gbcursor,
                                                       int* __restrict__ tmp) {
  __shared__ int hist[256];
  __shared__ int segcur[256];
  int tid = threadIdx.x;
  int estart = blockIdx.x * CHUNK;
  int eend = min(E, estart + CHUNK);
  hist[tid] = 0;
  __syncthreads();
  for (int i = estart + tid; i < eend; i += 256)
    atomicAdd(&hist[dst[i] >> BSHIFT], 1);
  __syncthreads();
  if (tid < nbc) {
    int c = hist[tid];
    segcur[tid] = c ? atomicAdd(&gbcursor[tid], c) : 0;
  }
  __syncthreads();
  for (int i = estart + tid; i < eend; i += 256) {
    int d = dst[i];
    int b = d >> BSHIFT;
    int pos = atomicAdd(&segcur[b], 1);
    if (pos < (b + 1) * CAP)  // statistically impossible overflow guard
      tmp[pos] = (src[i] << BSHIFT) | (d & BMASK);
  }
}

// One block per bucket: LDS degree hist -> LDS 512-scan (256 thr, pair trick)
// -> row_start/degs/dinv -> LDS-cursor scatter into bucket-local csr region.
__global__ __launch_bounds__(256) void csrbuild_kernel(const int* __restrict__ tmp,
                                                       const int* __restrict__ gbcursor,
                                                       int n, int* __restrict__ row_start,
                                                       int* __restrict__ degs,
                                                       float* __restrict__ dinv,
                                                       int* __restrict__ csr) {
  __shared__ int nh[512];
  __shared__ int sp[256];
  __shared__ int lcur[512];
  int b = blockIdx.x, tid = threadIdx.x;
  int base = b * CAP;
  int count = min(gbcursor[b] - base, CAP);
  nh[tid] = 0; nh[tid + 256] = 0;
  __syncthreads();
  for (int i = tid; i < count; i += 256) atomicAdd(&nh[tmp[base + i] & BMASK], 1);
  __syncthreads();
  int d0 = nh[2 * tid], d1 = nh[2 * tid + 1];
  int s = d0 + d1;
  sp[tid] = s;
  __syncthreads();
  for (int off = 1; off < 256; off <<= 1) {
    int a = sp[tid];
    int bb = (tid >= off) ? sp[tid - off] : 0;
    __syncthreads();
    sp[tid] = a + bb;
    __syncthreads();
  }
  int pp = sp[tid] - s;  // exclusive pair prefix
  int e0a = base + pp;
  int e0b = e0a + d0;
  lcur[2 * tid] = e0a;
  lcur[2 * tid + 1] = e0b;
  int vb = b << BSHIFT;
  int va = vb + 2 * tid;
  if (va < n) {
    row_start[va] = e0a; degs[va] = d0;
    dinv[va] = rsqrtf((float)(d0 + 1));
  }
  if (va + 1 < n) {
    row_start[va + 1] = e0b; degs[va + 1] = d1;
    dinv[va + 1] = rsqrtf((float)(d1 + 1));
  }
  __syncthreads();
  for (int i = tid; i < count; i += 256) {
    int val = tmp[base + i];
    int pos = atomicAdd(&lcur[val & BMASK], 1);
    csr[pos] = val >> BSHIFT;
  }
}

// h1s[row] = bf16x2-packed dinv[row] * (x[row] @ W1), via MFMA (R9-proven).
__global__ __launch_bounds__(256, 4) void gemm1_kernel(const float* __restrict__ x,
                                                       const float* __restrict__ W1,
                                                       const float* __restrict__ dinv,
                                                       unsigned* __restrict__ h1s, int n) {
  __shared__ unsigned lds_u[64 * 68 * 2];
  unsigned* xs = lds_u;
  unsigned* wt = lds_u + 64 * 68;
  int tid = threadIdx.x;
  int vb = blockIdx.x * 64;
  int nrows = min(64, n - vb);

  // stage x: coalesced float4 loads, pack to bf16x2
  const float4* xg = (const float4*)(x + (size_t)vb * 128);
#pragma unroll
  for (int it = 0; it < 8; ++it) {
    int idx = it * 256 + tid;
    int r = idx >> 5, c2 = idx & 31;
    float4 vv = make_float4(0.f, 0.f, 0.f, 0.f);
    if (r < nrows) vv = xg[idx];
    xs[r * 68 + c2 * 2] = (f2b(vv.y) << 16) | f2b(vv.x);
    xs[r * 68 + c2 * 2 + 1] = (f2b(vv.w) << 16) | f2b(vv.z);
  }
  // stage W1^T: wt16[n][k] bf16, stride 136 u16 (= 68 u32)
  unsigned short* wt16 = (unsigned short*)wt;
  const float4* wg = (const float4*)W1;
#pragma unroll
  for (int it = 0; it < 8; ++it) {
    int idx = it * 256 + tid;          // [0,2048): k = idx>>4, n0 = (idx&15)*4
    int k = idx >> 4, n0 = (idx & 15) * 4;
    float4 wv = wg[idx];
    wt16[(n0 + 0) * 136 + k] = (unsigned short)f2b(wv.x);
    wt16[(n0 + 1) * 136 + k] = (unsigned short)f2b(wv.y);
    wt16[(n0 + 2) * 136 + k] = (unsigned short)f2b(wv.z);
    wt16[(n0 + 3) * 136 + k] = (unsigned short)f2b(wv.w);
  }
  __syncthreads();

  int lane = tid & 63, wid = tid >> 6;
  int m16 = lane & 15, quad = lane >> 4;
  const unsigned* xp = xs + (wid * 16 + m16) * 68 + quad * 4;
  const unsigned* wp = wt + m16 * 68 + quad * 4;
  f32x4 acc[4] = {};
#pragma unroll
  for (int ks = 0; ks < 4; ++ks) {
    bf16x8 a = *(const bf16x8*)(xp + ks * 16);
#pragma unroll
    for (int nt = 0; nt < 4; ++nt) {
      bf16x8 b = *(const bf16x8*)(wp + nt * 16 * 68 + ks * 16);
      acc[nt] = __builtin_amdgcn_mfma_f32_16x16x32_bf16(a, b, acc[nt], 0, 0, 0);
    }
  }
  // epilogue: C[row = quad*4+reg][col = nt*16+m16]; fold dinv, pack bf16
  int rbase = vb + wid * 16 + quad * 4;
  float dvv[4];
#pragma unroll
  for (int reg = 0; reg < 4; ++reg) {
    int row = rbase + reg;
    dvv[reg] = (row < n) ? dinv[row] : 0.f;
  }
  unsigned short* h16 = (unsigned short*)h1s;
#pragma unroll
  for (int nt = 0; nt < 4; ++nt) {
    int col = nt * 16 + m16;
#pragma unroll
    for (int reg = 0; reg < 4; ++reg) {
      int row = rbase + reg;
      if (row < n)
        h16[(size_t)row * 64 + col] = (unsigned short)f2b(dvv[reg] * acc[nt][reg]);
    }
  }
}

struct f2 { float x, y; };
__device__ __forceinline__ void addu(f2& a, unsigned u) {
  a.x += __uint_as_float(u << 16);
  a.y += __uint_as_float(u);  // low 16 bits are mantissa noise (<=0.4% rel)
}
__device__ __forceinline__ void addu4(f2* a, uint4 g) {
  addu(a[0], g.x); addu(a[1], g.y); addu(a[2], g.z); addu(a[3], g.w);
}

// Half-wave per node: lanes 0-31 node A, 32-63 node B. sub=lane&31:
// e=sub>>3 in [0,4) (edge slot), c=sub&7 (16B chunk). Per iter: 2 uint4
// gathers cover 8 edges of BOTH nodes (4 gathers in flight/wave + selves).
// Row n of h1s is zeros -> masked tails branch-free. Grid-stride, 8 nodes/blk.
__global__ __launch_bounds__(256) void agg1_kernel(const uint4* __restrict__ h1s4,
                                                   const float* __restrict__ dinv,
                                                   const int* __restrict__ row_start,
                                                   const int* __restrict__ degs,
                                                   const int* __restrict__ csr,
                                                   const float* __restrict__ b1,
                                                   const float* __restrict__ W2,
                                                   unsigned* __restrict__ t, int n) {
  __shared__ float W2s[64 * 17];
  __shared__ float b1s[64];
  __shared__ float a_s[4][2][64];
  for (int i = threadIdx.x; i < 1024; i += 256)
    W2s[(i >> 4) * 17 + (i & 15)] = W2[i];
  if (threadIdx.x < 64) b1s[threadIdx.x] = b1[threadIdx.x];
  // zero t row n for agg2's masked gathers (tmp alias is dead by now)
  if (blockIdx.x == 0 && threadIdx.x < 8) t[(size_t)n * 8 + threadIdx.x] = 0u;
  __syncthreads();

  int wave = threadIdx.x >> 6, lane = threadIdx.x & 63;
  int half = lane >> 5, sub = lane & 31;
  int e = sub >> 3, c = sub & 7;
  int j = sub & 15, grp = (sub >> 4) & 1;

  for (int vbase = blockIdx.x * 8; vbase < n; vbase += gridDim.x * 8) {
    int v = vbase + wave * 2 + half;
    bool valid = (v < n);            // half-uniform
    int vc = valid ? v : 0;
    int i = row_start[vc];
    int e1 = i + (valid ? degs[vc] : 0);
    float dv = valid ? dinv[vc] : 0.f;

    f2 a0[4];
#pragma unroll
    for (int k = 0; k < 4; ++k) a0[k] = {0.f, 0.f};
    {  // self loop: e==0 lanes pull row v (c=sub), others pull zero row
      int s = (valid && sub < 8) ? v : n;
      addu4(a0, h1s4[(size_t)s * 8 + c]);
    }
    while (__any(i < e1)) {
      int i0 = i + e, i1 = i + 4 + e;
      int s0v = csr[i0];              // padded/bucket-gap reads are safe
      int s1v = csr[i1];
      int s0 = (i0 < e1) ? s0v : n;
      int s1 = (i1 < e1) ? s1v : n;
      uint4 g0 = h1s4[(size_t)s0 * 8 + c];
      uint4 g1 = h1s4[(size_t)s1 * 8 + c];
      addu4(a0, g0);
      addu4(a0, g1);
      i += 8;
    }
    // reduce across e (lane bits 3,4 within half): 2 levels
#pragma unroll
    for (int m = 8; m <= 16; m <<= 1) {
#pragma unroll
      for (int k = 0; k < 4; ++k) {
        a0[k].x += __shfl_xor(a0[k].x, m, 64);
        a0[k].y += __shfl_xor(a0[k].y, m, 64);
      }
    }
    if (sub < 8) {  // e==0; c==sub; features 8c..8c+7
#pragma unroll
      for (int k = 0; k < 4; ++k) {
        float z0 = fmaf(dv, a0[k].x, b1s[8 * sub + 2 * k]);
        float z1 = fmaf(dv, a0[k].y, b1s[8 * sub + 2 * k + 1]);
        a_s[wave][half][8 * sub + 2 * k] = fmaxf(z0, 0.2f * z0);
        a_s[wave][half][8 * sub + 2 * k + 1] = fmaxf(z1, 0.2f * z1);
      }
    }
    // MLP 64->16: each half-lane sums 32 features (grp*16 and 32+grp*16)
    float p = 0.f;
#pragma unroll
    for (int q = 0; q < 16; ++q) {
      int f = grp * 16 + q;
      p = fmaf(a_s[wave][half][f], W2s[f * 17 + j], p);
    }
#pragma unroll
    for (int q = 0; q < 16; ++q) {
      int f = 32 + grp * 16 + q;
      p = fmaf(a_s[wave][half][f], W2s[f * 17 + j], p);
    }
    p += __shfl_xor(p, 16, 64);  // combine grp halves (lane bit 4)
    // pack pairs: sub<16 holds feature j; even subs write u32 (j, j+1)
    float pv = dv * p;
    float po = __shfl_xor(pv, 1, 64);
    if (valid && sub < 16 && !(sub & 1))
      t[(size_t)v * 8 + (sub >> 1)] = (f2b(po) << 16) | f2b(pv);
  }
}

// 16 lanes per node, bf16 t rows (32B). sub=lane&15: e=sub>>1 (8 edge slots),
// c=sub&1 (uint4 half = features 8c..8c+7). One wave-load = 8 edges x 4 nodes.
// Row n of t is zeros. log_softmax via 8-local + xor-1 lane reduce.
__global__ __launch_bounds__(256) void agg2_kernel(const uint4* __restrict__ t4,
                                                   const float* __restrict__ dinv,
                                                   const int* __restrict__ row_start,
                                                   const int* __restrict__ degs,
                                                   const int* __restrict__ csr,
                                                   const float* __restrict__ b2,
                                                   float* __restrict__ out, int n) {
  int idx = blockIdx.x * 256 + threadIdx.x;
  int v = idx >> 4;
  if (v >= n) return;
  int sub = threadIdx.x & 15;
  int e = sub >> 1, c = sub & 1;
  float dv = dinv[v];
  int e0 = row_start[v], e1 = e0 + degs[v];
  f2 A0[4], A1[4];
#pragma unroll
  for (int k = 0; k < 4; ++k) { A0[k] = {0.f, 0.f}; A1[k] = {0.f, 0.f}; }
  {  // self loop
    int s = (e == 0) ? v : n;
    addu4(A0, t4[(size_t)s * 2 + c]);
  }
  int i = e0;
  while (i + 8 < e1) {
    int i1 = i + 8 + e;
    int s0 = csr[i + e];
    int s1v = csr[i1];
    int s1 = (i1 < e1) ? s1v : n;
    uint4 g0 = t4[(size_t)s0 * 2 + c];
    uint4 g1 = t4[(size_t)s1 * 2 + c];
    addu4(A0, g0);
    addu4(A1, g1);
    i += 16;
  }
  if (i < e1) {
    int i0 = i + e;
    int sv = csr[i0];
    int s = (i0 < e1) ? sv : n;
    addu4(A0, t4[(size_t)s * 2 + c]);
  }
#pragma unroll
  for (int k = 0; k < 4; ++k) { A0[k].x += A1[k].x; A0[k].y += A1[k].y; }
#pragma unroll
  for (int m = 2; m <= 8; m <<= 1) {  // reduce across e-groups (sub bits 1..3)
#pragma unroll
    for (int k = 0; k < 4; ++k) {
      A0[k].x += __shfl_xor(A0[k].x, m, 64);
      A0[k].y += __shfl_xor(A0[k].y, m, 64);
    }
  }
  // z for features 8c..8c+7
  float4 bb0 = ((const float4*)b2)[c * 2];
  float4 bb1 = ((const float4*)b2)[c * 2 + 1];
  float z[8];
  z[0] = fmaf(dv, A0[0].x, bb0.x); z[1] = fmaf(dv, A0[0].y, bb0.y);
  z[2] = fmaf(dv, A0[1].x, bb0.z); z[3] = fmaf(dv, A0[1].y, bb0.w);
  z[4] = fmaf(dv, A0[2].x, bb1.x); z[5] = fmaf(dv, A0[2].y, bb1.y);
  z[6] = fmaf(dv, A0[3].x, bb1.z); z[7] = fmaf(dv, A0[3].y, bb1.w);
  float mx = z[0];
#pragma unroll
  for (int q = 1; q < 8; ++q) mx = fmaxf(mx, z[q]);
  mx = fmaxf(mx, __shfl_xor(mx, 1, 64));  // combine c halves
  float ss = 0.f;
#pragma unroll
  for (int q = 0; q < 8; ++q) ss += expf(z[q] - mx);
  ss += __shfl_xor(ss, 1, 64);
  float lg = mx + logf(ss);
  if (e == 0) {
    float4 r0 = make_float4(z[0] - lg, z[1] - lg, z[2] - lg, z[3] - lg);
    float4 r1 = make_float4(z[4] - lg, z[5] - lg, z[6] - lg, z[7] - lg);
    float4* o = (float4*)out + (size_t)v * 4 + c * 2;
    o[0] = r0;
    o[1] = r1;
  }
}

extern "C" void kernel_launch(void* const* d_in, const int* in_sizes, int n_in,
                              void* d_out, int out_size, void* d_ws, size_t ws_size,
                              hipStream_t stream) {
  const float* x = (const float*)d_in[0];
  const int* edge_index = (const int*)d_in[1];
  const float* W1 = (const float*)d_in[2];
  const float* b1 = (const float*)d_in[3];
  const float* W2 = (const float*)d_in[4];
  const float* b2 = (const float*)d_in[5];
  float* out = (float*)d_out;

  int N_ = in_sizes[0] / 128;
  int E_ = in_sizes[1] / 2;
  const int* src = edge_index;
  const int* dst = edge_index + E_;
  int NBc = (N_ + BMASK) >> BSHIFT;  // 196 buckets of 512 nodes (<= 256)

  char* ws = (char*)d_ws;
  size_t off = 0;
  auto take = [&](size_t bytes) {
    void* p = ws + off;
    off += (bytes + 255) & ~(size_t)255;
    return p;
  };
  unsigned* h1s = (unsigned*)take(((size_t)N_ + 1) * 32 * 4);  // +1 zero row
  // t ((N+1)*8*4 bf16-packed) aliases tmp (NBc*CAP*4): tmp dead before agg1.
  size_t t_bytes = ((size_t)N_ + 1) * 8 * 4, tmp_bytes = (size_t)NBc * CAP * 4;
  void* t_union = take(t_bytes > tmp_bytes ? t_bytes : tmp_bytes);
  unsigned* t = (unsigned*)t_union;
  int* tmp = (int*)t_union;
  float* dinv = (float*)take((size_t)N_ * 4);
  int* degs = (int*)take((size_t)N_ * 4);
  int* row_start = (int*)take(((size_t)N_ + 1) * 4);
  int* csr = (int*)take(((size_t)NBc * CAP + 16) * 4);  // bucket-local + pad
  int* gbcursor = (int*)take((size_t)NBc * 4);
  (void)ws_size;

  binit_kernel<<<(NBc + 255) / 256, 256, 0, stream>>>(gbcursor, NBc, h1s, N_);
  scatterA_kernel<<<(E_ + CHUNK - 1) / CHUNK, 256, 0, stream>>>(src, dst, E_, NBc,
                                                                gbcursor, tmp);
  csrbuild_kernel<<<NBc, 256, 0, stream>>>(tmp, gbcursor, N_, row_start, degs,
                                           dinv, csr);
  gemm1_kernel<<<(N_ + 63) / 64, 256, 0, stream>>>(x, W1, dinv, h1s, N_);
  agg1_kernel<<<2048, 256, 0, stream>>>((const uint4*)h1s, dinv, row_start, degs,
                                        csr, b1, W2, t, N_);
  agg2_kernel<<<(N_ * 16 + 255) / 256, 256, 0, stream>>>((const uint4*)t, dinv,
                                                         row_start, degs, csr,
                                                         b2, out, N_);
}

// Round 11
// 227.279 us; speedup vs baseline: 1.2132x; 1.0017x over previous
//
#include <hip/hip_runtime.h>
#include <math.h>

// ---------------------------------------------------------------------------
// 2-layer GCN. R11: agg1 edge loop unrolled x2 -> 4 uint4 gathers in flight
// per lane per iteration (16 edges/node/iter; deg~16 completes in ONE iter).
// R10 evidence: throughput scales with outstanding requests (1.47->1.83 TB/s
// when in-flight doubled); VALU 39% / BW 22% -> still latency-bound.
// Two accumulator chains for ILP; VGPR budget watched (<=64 for 8 waves/SIMD).
// ---------------------------------------------------------------------------

#define CHUNK 8192        // edges per scatterA block
#define BSHIFT 9          // 512 nodes per bucket
#define BMASK 511
#define CAP 9216          // tmp/csr slots per bucket (mean 8192, +11 sigma)

typedef __bf16 bf16x8 __attribute__((ext_vector_type(8)));
typedef float f32x4 __attribute__((ext_vector_type(4)));

__device__ __forceinline__ unsigned f2b(float f) {  // fp32 -> bf16 bits (RNE)
  unsigned u = __float_as_uint(f);
  return (u + 0x7FFF + ((u >> 16) & 1)) >> 16;
}

// init bucket cursors + zero h1s row n (the "zero row" for masked gathers)
__global__ void binit_kernel(int* __restrict__ gbcursor, int nbc,
                             unsigned* __restrict__ h1s, int n) {
  int b = blockIdx.x * 256 + threadIdx.x;
  if (b < nbc) gbcursor[b] = b * CAP;
  if (blockIdx.x == 0 && threadIdx.x < 32) h1s[(size_t)n * 32 + threadIdx.x] = 0u;
}

// Block multisplit: pass1 LDS bucket hist; one global atomic per (block,bucket)
// reserves a segment; pass2 places edges via LDS cursors. pack=(src<<9)|(dst&511).
__global__ __launch_bounds__(256) void scatterA_kernel(const int* __restrict__ src,
                                                       const int* __restrict__ dst,
                                                       int E, int nbc,
                                                       int* __restrict__ gbcursor,
                                                       int* __restrict__ tmp) {
  __shared__ int hist[256];
  __shared__ int segcur[256];
  int tid = threadIdx.x;
  int estart = blockIdx.x * CHUNK;
  int eend = min(E, estart + CHUNK);
  hist[tid] = 0;
  __syncthreads();
  for (int i = estart + tid; i < eend; i += 256)
    atomicAdd(&hist[dst[i] >> BSHIFT], 1);
  __syncthreads();
  if (tid < nbc) {
    int c = hist[tid];
    segcur[tid] = c ? atomicAdd(&gbcursor[tid], c) : 0;
  }
  __syncthreads();
  for (int i = estart + tid; i < eend; i += 256) {
    int d = dst[i];
    int b = d >> BSHIFT;
    int pos = atomicAdd(&segcur[b], 1);
    if (pos < (b + 1) * CAP)  // statistically impossible overflow guard
      tmp[pos] = (src[i] << BSHIFT) | (d & BMASK);
  }
}

// One block per bucket: LDS degree hist -> LDS 512-scan (256 thr, pair trick)
// -> row_start/degs/dinv -> LDS-cursor scatter into bucket-local csr region.
__global__ __launch_bounds__(256) void csrbuild_kernel(const int* __restrict__ tmp,
                                                       const int* __restrict__ gbcursor,
                                                       int n, int* __restrict__ row_start,
                                                       int* __restrict__ degs,
                                                       float* __restrict__ dinv,
                                                       int* __restrict__ csr) {
  __shared__ int nh[512];
  __shared__ int sp[256];
  __shared__ int lcur[512];
  int b = blockIdx.x, tid = threadIdx.x;
  int base = b * CAP;
  int count = min(gbcursor[b] - base, CAP);
  nh[tid] = 0; nh[tid + 256] = 0;
  __syncthreads();
  for (int i = tid; i < count; i += 256) atomicAdd(&nh[tmp[base + i] & BMASK], 1);
  __syncthreads();
  int d0 = nh[2 * tid], d1 = nh[2 * tid + 1];
  int s = d0 + d1;
  sp[tid] = s;
  __syncthreads();
  for (int off = 1; off < 256; off <<= 1) {
    int a = sp[tid];
    int bb = (tid >= off) ? sp[tid - off] : 0;
    __syncthreads();
    sp[tid] = a + bb;
    __syncthreads();
  }
  int pp = sp[tid] - s;  // exclusive pair prefix
  int e0a = base + pp;
  int e0b = e0a + d0;
  lcur[2 * tid] = e0a;
  lcur[2 * tid + 1] = e0b;
  int vb = b << BSHIFT;
  int va = vb + 2 * tid;
  if (va < n) {
    row_start[va] = e0a; degs[va] = d0;
    dinv[va] = rsqrtf((float)(d0 + 1));
  }
  if (va + 1 < n) {
    row_start[va + 1] = e0b; degs[va + 1] = d1;
    dinv[va + 1] = rsqrtf((float)(d1 + 1));
  }
  __syncthreads();
  for (int i = tid; i < count; i += 256) {
    int val = tmp[base + i];
    int pos = atomicAdd(&lcur[val & BMASK], 1);
    csr[pos] = val >> BSHIFT;
  }
}

// h1s[row] = bf16x2-packed dinv[row] * (x[row] @ W1), via MFMA (R9-proven).
__global__ __launch_bounds__(256, 4) void gemm1_kernel(const float* __restrict__ x,
                                                       const float* __restrict__ W1,
                                                       const float* __restrict__ dinv,
                                                       unsigned* __restrict__ h1s, int n) {
  __shared__ unsigned lds_u[64 * 68 * 2];
  unsigned* xs = lds_u;
  unsigned* wt = lds_u + 64 * 68;
  int tid = threadIdx.x;
  int vb = blockIdx.x * 64;
  int nrows = min(64, n - vb);

  // stage x: coalesced float4 loads, pack to bf16x2
  const float4* xg = (const float4*)(x + (size_t)vb * 128);
#pragma unroll
  for (int it = 0; it < 8; ++it) {
    int idx = it * 256 + tid;
    int r = idx >> 5, c2 = idx & 31;
    float4 vv = make_float4(0.f, 0.f, 0.f, 0.f);
    if (r < nrows) vv = xg[idx];
    xs[r * 68 + c2 * 2] = (f2b(vv.y) << 16) | f2b(vv.x);
    xs[r * 68 + c2 * 2 + 1] = (f2b(vv.w) << 16) | f2b(vv.z);
  }
  // stage W1^T: wt16[n][k] bf16, stride 136 u16 (= 68 u32)
  unsigned short* wt16 = (unsigned short*)wt;
  const float4* wg = (const float4*)W1;
#pragma unroll
  for (int it = 0; it < 8; ++it) {
    int idx = it * 256 + tid;          // [0,2048): k = idx>>4, n0 = (idx&15)*4
    int k = idx >> 4, n0 = (idx & 15) * 4;
    float4 wv = wg[idx];
    wt16[(n0 + 0) * 136 + k] = (unsigned short)f2b(wv.x);
    wt16[(n0 + 1) * 136 + k] = (unsigned short)f2b(wv.y);
    wt16[(n0 + 2) * 136 + k] = (unsigned short)f2b(wv.z);
    wt16[(n0 + 3) * 136 + k] = (unsigned short)f2b(wv.w);
  }
  __syncthreads();

  int lane = tid & 63, wid = tid >> 6;
  int m16 = lane & 15, quad = lane >> 4;
  const unsigned* xp = xs + (wid * 16 + m16) * 68 + quad * 4;
  const unsigned* wp = wt + m16 * 68 + quad * 4;
  f32x4 acc[4] = {};
#pragma unroll
  for (int ks = 0; ks < 4; ++ks) {
    bf16x8 a = *(const bf16x8*)(xp + ks * 16);
#pragma unroll
    for (int nt = 0; nt < 4; ++nt) {
      bf16x8 b = *(const bf16x8*)(wp + nt * 16 * 68 + ks * 16);
      acc[nt] = __builtin_amdgcn_mfma_f32_16x16x32_bf16(a, b, acc[nt], 0, 0, 0);
    }
  }
  // epilogue: C[row = quad*4+reg][col = nt*16+m16]; fold dinv, pack bf16
  int rbase = vb + wid * 16 + quad * 4;
  float dvv[4];
#pragma unroll
  for (int reg = 0; reg < 4; ++reg) {
    int row = rbase + reg;
    dvv[reg] = (row < n) ? dinv[row] : 0.f;
  }
  unsigned short* h16 = (unsigned short*)h1s;
#pragma unroll
  for (int nt = 0; nt < 4; ++nt) {
    int col = nt * 16 + m16;
#pragma unroll
    for (int reg = 0; reg < 4; ++reg) {
      int row = rbase + reg;
      if (row < n)
        h16[(size_t)row * 64 + col] = (unsigned short)f2b(dvv[reg] * acc[nt][reg]);
    }
  }
}

struct f2 { float x, y; };
__device__ __forceinline__ void addu(f2& a, unsigned u) {
  a.x += __uint_as_float(u << 16);
  a.y += __uint_as_float(u);  // low 16 bits are mantissa noise (<=0.4% rel)
}
__device__ __forceinline__ void addu4(f2* a, uint4 g) {
  addu(a[0], g.x); addu(a[1], g.y); addu(a[2], g.z); addu(a[3], g.w);
}

// Half-wave per node: lanes 0-31 node A, 32-63 node B. sub=lane&31:
// e=sub>>3 in [0,4), c=sub&7 (16B chunk). Edge loop unrolled x2: 4 uint4
// gathers in flight covering 16 edges/node/iter (deg~16 -> single iter).
// Row n of h1s is zeros -> masked tails branch-free. Grid-stride, 8 nodes/blk.
__global__ __launch_bounds__(256) void agg1_kernel(const uint4* __restrict__ h1s4,
                                                   const float* __restrict__ dinv,
                                                   const int* __restrict__ row_start,
                                                   const int* __restrict__ degs,
                                                   const int* __restrict__ csr,
                                                   const float* __restrict__ b1,
                                                   const float* __restrict__ W2,
                                                   unsigned* __restrict__ t, int n) {
  __shared__ float W2s[64 * 17];
  __shared__ float b1s[64];
  __shared__ float a_s[4][2][64];
  for (int i = threadIdx.x; i < 1024; i += 256)
    W2s[(i >> 4) * 17 + (i & 15)] = W2[i];
  if (threadIdx.x < 64) b1s[threadIdx.x] = b1[threadIdx.x];
  // zero t row n for agg2's masked gathers (tmp alias is dead by now)
  if (blockIdx.x == 0 && threadIdx.x < 8) t[(size_t)n * 8 + threadIdx.x] = 0u;
  __syncthreads();

  int wave = threadIdx.x >> 6, lane = threadIdx.x & 63;
  int half = lane >> 5, sub = lane & 31;
  int e = sub >> 3, c = sub & 7;
  int j = sub & 15, grp = (sub >> 4) & 1;

  for (int vbase = blockIdx.x * 8; vbase < n; vbase += gridDim.x * 8) {
    int v = vbase + wave * 2 + half;
    bool valid = (v < n);            // half-uniform
    int vc = valid ? v : 0;
    int i = row_start[vc];
    int e1 = i + (valid ? degs[vc] : 0);
    float dv = valid ? dinv[vc] : 0.f;

    f2 a0[4], a1[4];
#pragma unroll
    for (int k = 0; k < 4; ++k) { a0[k] = {0.f, 0.f}; a1[k] = {0.f, 0.f}; }
    {  // self loop: e==0 lanes pull row v (c=sub), others pull zero row
      int s = (valid && sub < 8) ? v : n;
      addu4(a0, h1s4[(size_t)s * 8 + c]);
    }
    while (__any(i < e1)) {
      int i0 = i + e, i1 = i + 4 + e, i2 = i + 8 + e, i3 = i + 12 + e;
      int s0v = csr[i0];              // padded/bucket-gap reads are safe
      int s1v = csr[i1];
      int s2v = csr[i2];
      int s3v = csr[i3];
      int s0 = (i0 < e1) ? s0v : n;
      int s1 = (i1 < e1) ? s1v : n;
      int s2 = (i2 < e1) ? s2v : n;
      int s3 = (i3 < e1) ? s3v : n;
      uint4 g0 = h1s4[(size_t)s0 * 8 + c];
      uint4 g1 = h1s4[(size_t)s1 * 8 + c];
      uint4 g2 = h1s4[(size_t)s2 * 8 + c];
      uint4 g3 = h1s4[(size_t)s3 * 8 + c];
      addu4(a0, g0);
      addu4(a1, g1);
      addu4(a0, g2);
      addu4(a1, g3);
      i += 16;
    }
#pragma unroll
    for (int k = 0; k < 4; ++k) { a0[k].x += a1[k].x; a0[k].y += a1[k].y; }
    // reduce across e (lane bits 3,4 within half): 2 levels
#pragma unroll
    for (int m = 8; m <= 16; m <<= 1) {
#pragma unroll
      for (int k = 0; k < 4; ++k) {
        a0[k].x += __shfl_xor(a0[k].x, m, 64);
        a0[k].y += __shfl_xor(a0[k].y, m, 64);
      }
    }
    if (sub < 8) {  // e==0; c==sub; features 8c..8c+7
#pragma unroll
      for (int k = 0; k < 4; ++k) {
        float z0 = fmaf(dv, a0[k].x, b1s[8 * sub + 2 * k]);
        float z1 = fmaf(dv, a0[k].y, b1s[8 * sub + 2 * k + 1]);
        a_s[wave][half][8 * sub + 2 * k] = fmaxf(z0, 0.2f * z0);
        a_s[wave][half][8 * sub + 2 * k + 1] = fmaxf(z1, 0.2f * z1);
      }
    }
    // MLP 64->16: each half-lane sums 32 features (grp*16 and 32+grp*16)
    float p = 0.f;
#pragma unroll
    for (int q = 0; q < 16; ++q) {
      int f = grp * 16 + q;
      p = fmaf(a_s[wave][half][f], W2s[f * 17 + j], p);
    }
#pragma unroll
    for (int q = 0; q < 16; ++q) {
      int f = 32 + grp * 16 + q;
      p = fmaf(a_s[wave][half][f], W2s[f * 17 + j], p);
    }
    p += __shfl_xor(p, 16, 64);  // combine grp halves (lane bit 4)
    // pack pairs: sub<16 holds feature j; even subs write u32 (j, j+1)
    float pv = dv * p;
    float po = __shfl_xor(pv, 1, 64);
    if (valid && sub < 16 && !(sub & 1))
      t[(size_t)v * 8 + (sub >> 1)] = (f2b(po) << 16) | f2b(pv);
  }
}

// 16 lanes per node, bf16 t rows (32B). sub=lane&15: e=sub>>1 (8 edge slots),
// c=sub&1 (uint4 half = features 8c..8c+7). One wave-load = 8 edges x 4 nodes.
// Row n of t is zeros. log_softmax via 8-local + xor-1 lane reduce.
__global__ __launch_bounds__(256) void agg2_kernel(const uint4* __restrict__ t4,
                                                   const float* __restrict__ dinv,
                                                   const int* __restrict__ row_start,
                                                   const int* __restrict__ degs,
                                                   const int* __restrict__ csr,
                                                   const float* __restrict__ b2,
                                                   float* __restrict__ out, int n) {
  int idx = blockIdx.x * 256 + threadIdx.x;
  int v = idx >> 4;
  if (v >= n) return;
  int sub = threadIdx.x & 15;
  int e = sub >> 1, c = sub & 1;
  float dv = dinv[v];
  int e0 = row_start[v], e1 = e0 + degs[v];
  f2 A0[4], A1[4];
#pragma unroll
  for (int k = 0; k < 4; ++k) { A0[k] = {0.f, 0.f}; A1[k] = {0.f, 0.f}; }
  {  // self loop
    int s = (e == 0) ? v : n;
    addu4(A0, t4[(size_t)s * 2 + c]);
  }
  int i = e0;
  while (i + 8 < e1) {
    int i1 = i + 8 + e;
    int s0 = csr[i + e];
    int s1v = csr[i1];
    int s1 = (i1 < e1) ? s1v : n;
    uint4 g0 = t4[(size_t)s0 * 2 + c];
    uint4 g1 = t4[(size_t)s1 * 2 + c];
    addu4(A0, g0);
    addu4(A1, g1);
    i += 16;
  }
  if (i < e1) {
    int i0 = i + e;
    int sv = csr[i0];
    int s = (i0 < e1) ? sv : n;
    addu4(A0, t4[(size_t)s * 2 + c]);
  }
#pragma unroll
  for (int k = 0; k < 4; ++k) { A0[k].x += A1[k].x; A0[k].y += A1[k].y; }
#pragma unroll
  for (int m = 2; m <= 8; m <<= 1) {  // reduce across e-groups (sub bits 1..3)
#pragma unroll
    for (int k = 0; k < 4; ++k) {
      A0[k].x += __shfl_xor(A0[k].x, m, 64);
      A0[k].y += __shfl_xor(A0[k].y, m, 64);
    }
  }
  // z for features 8c..8c+7
  float4 bb0 = ((const float4*)b2)[c * 2];
  float4 bb1 = ((const float4*)b2)[c * 2 + 1];
  float z[8];
  z[0] = fmaf(dv, A0[0].x, bb0.x); z[1] = fmaf(dv, A0[0].y, bb0.y);
  z[2] = fmaf(dv, A0[1].x, bb0.z); z[3] = fmaf(dv, A0[1].y, bb0.w);
  z[4] = fmaf(dv, A0[2].x, bb1.x); z[5] = fmaf(dv, A0[2].y, bb1.y);
  z[6] = fmaf(dv, A0[3].x, bb1.z); z[7] = fmaf(dv, A0[3].y, bb1.w);
  float mx = z[0];
#pragma unroll
  for (int q = 1; q < 8; ++q) mx = fmaxf(mx, z[q]);
  mx = fmaxf(mx, __shfl_xor(mx, 1, 64));  // combine c halves
  float ss = 0.f;
#pragma unroll
  for (int q = 0; q < 8; ++q) ss += expf(z[q] - mx);
  ss += __shfl_xor(ss, 1, 64);
  float lg = mx + logf(ss);
  if (e == 0) {
    float4 r0 = make_float4(z[0] - lg, z[1] - lg, z[2] - lg, z[3] - lg);
    float4 r1 = make_float4(z[4] - lg, z[5] - lg, z[6] - lg, z[7] - lg);
    float4* o = (float4*)out + (size_t)v * 4 + c * 2;
    o[0] = r0;
    o[1] = r1;
  }
}

extern "C" void kernel_launch(void* const* d_in, const int* in_sizes, int n_in,
                              void* d_out, int out_size, void* d_ws, size_t ws_size,
                              hipStream_t stream) {
  const float* x = (const float*)d_in[0];
  const int* edge_index = (const int*)d_in[1];
  const float* W1 = (const float*)d_in[2];
  const float* b1 = (const float*)d_in[3];
  const float* W2 = (const float*)d_in[4];
  const float* b2 = (const float*)d_in[5];
  float* out = (float*)d_out;

  int N_ = in_sizes[0] / 128;
  int E_ = in_sizes[1] / 2;
  const int* src = edge_index;
  const int* dst = edge_index + E_;
  int NBc = (N_ + BMASK) >> BSHIFT;  // 196 buckets of 512 nodes (<= 256)

  char* ws = (char*)d_ws;
  size_t off = 0;
  auto take = [&](size_t bytes) {
    void* p = ws + off;
    off += (bytes + 255) & ~(size_t)255;
    return p;
  };
  unsigned* h1s = (unsigned*)take(((size_t)N_ + 1) * 32 * 4);  // +1 zero row
  // t ((N+1)*8*4 bf16-packed) aliases tmp (NBc*CAP*4): tmp dead before agg1.
  size_t t_bytes = ((size_t)N_ + 1) * 8 * 4, tmp_bytes = (size_t)NBc * CAP * 4;
  void* t_union = take(t_bytes > tmp_bytes ? t_bytes : tmp_bytes);
  unsigned* t = (unsigned*)t_union;
  int* tmp = (int*)t_union;
  float* dinv = (float*)take((size_t)N_ * 4);
  int* degs = (int*)take((size_t)N_ * 4);
  int* row_start = (int*)take(((size_t)N_ + 1) * 4);
  int* csr = (int*)take(((size_t)NBc * CAP + 16) * 4);  // bucket-local + pad
  int* gbcursor = (int*)take((size_t)NBc * 4);
  (void)ws_size;

  binit_kernel<<<(NBc + 255) / 256, 256, 0, stream>>>(gbcursor, NBc, h1s, N_);
  scatterA_kernel<<<(E_ + CHUNK - 1) / CHUNK, 256, 0, stream>>>(src, dst, E_, NBc,
                                                                gbcursor, tmp);
  csrbuild_kernel<<<NBc, 256, 0, stream>>>(tmp, gbcursor, N_, row_start, degs,
                                           dinv, csr);
  gemm1_kernel<<<(N_ + 63) / 64, 256, 0, stream>>>(x, W1, dinv, h1s, N_);
  agg1_kernel<<<2048, 256, 0, stream>>>((const uint4*)h1s, dinv, row_start, degs,
                                        csr, b1, W2, t, N_);
  agg2_kernel<<<(N_ * 16 + 255) / 256, 256, 0, stream>>>((const uint4*)t, dinv,
                                                         row_start, degs, csr,
                                                         b2, out, N_);
}

// Round 12
// 210.742 us; speedup vs baseline: 1.3084x; 1.0785x over previous
//
#include <hip/hip_runtime.h>
#include <math.h>

// ---------------------------------------------------------------------------
// 2-layer GCN. R12: parallelize the CSR-build pipeline (the hidden ~177us).
//  - scatterA: CHUNK 8192->4096 (196->391 blocks; 2x parallelism, LDS-atomic
//    iterations halved per pass). ~10MB extra boundary-line writes accepted.
//  - csrbuild: 256->1024 threads/block (histogram + scatter passes 32->8
//    iterations; 512-entry scan on 512 active lanes).
//  - agg1 reverted to R10 loop (R11 unroll was neutral; VGPR 56->40).
// agg1 itself is at its structural floor: 84MB beyond-L2 traffic = random
// 12.8MB working set vs 4MB/XCD L2 (~20-30% max hit), 1.8TB/s achieved.
// ---------------------------------------------------------------------------

#define CHUNK 4096        // edges per scatterA block
#define BSHIFT 9          // 512 nodes per bucket
#define BMASK 511
#define CAP 9216          // tmp/csr slots per bucket (mean 8192, +11 sigma)

typedef __bf16 bf16x8 __attribute__((ext_vector_type(8)));
typedef float f32x4 __attribute__((ext_vector_type(4)));

__device__ __forceinline__ unsigned f2b(float f) {  // fp32 -> bf16 bits (RNE)
  unsigned u = __float_as_uint(f);
  return (u + 0x7FFF + ((u >> 16) & 1)) >> 16;
}

// init bucket cursors + zero h1s row n (the "zero row" for masked gathers)
__global__ void binit_kernel(int* __restrict__ gbcursor, int nbc,
                             unsigned* __restrict__ h1s, int n) {
  int b = blockIdx.x * 256 + threadIdx.x;
  if (b < nbc) gbcursor[b] = b * CAP;
  if (blockIdx.x == 0 && threadIdx.x < 32) h1s[(size_t)n * 32 + threadIdx.x] = 0u;
}

// Block multisplit: pass1 LDS bucket hist; one global atomic per (block,bucket)
// reserves a segment; pass2 places edges via LDS cursors. pack=(src<<9)|(dst&511).
__global__ __launch_bounds__(256) void scatterA_kernel(const int* __restrict__ src,
                                                       const int* __restrict__ dst,
                                                       int E, int nbc,
                                                       int* __restrict__ gbcursor,
                                                       int* __restrict__ tmp) {
  __shared__ int hist[256];
  __shared__ int segcur[256];
  int tid = threadIdx.x;
  int estart = blockIdx.x * CHUNK;
  int eend = min(E, estart + CHUNK);
  hist[tid] = 0;
  __syncthreads();
  for (int i = estart + tid; i < eend; i += 256)
    atomicAdd(&hist[dst[i] >> BSHIFT], 1);
  __syncthreads();
  if (tid < nbc) {
    int c = hist[tid];
    segcur[tid] = c ? atomicAdd(&gbcursor[tid], c) : 0;
  }
  __syncthreads();
  for (int i = estart + tid; i < eend; i += 256) {
    int d = dst[i];
    int b = d >> BSHIFT;
    int pos = atomicAdd(&segcur[b], 1);
    if (pos < (b + 1) * CAP)  // statistically impossible overflow guard
      tmp[pos] = (src[i] << BSHIFT) | (d & BMASK);
  }
}

// One block (1024 thr) per bucket: LDS degree hist -> 512-scan -> row_start/
// degs/dinv -> LDS-cursor scatter into bucket-local csr region.
__global__ __launch_bounds__(1024) void csrbuild_kernel(const int* __restrict__ tmp,
                                                        const int* __restrict__ gbcursor,
                                                        int n, int* __restrict__ row_start,
                                                        int* __restrict__ degs,
                                                        float* __restrict__ dinv,
                                                        int* __restrict__ csr) {
  __shared__ int nh[512];
  __shared__ int sc[512];
  __shared__ int lcur[512];
  int b = blockIdx.x, tid = threadIdx.x;
  int base = b * CAP;
  int count = min(gbcursor[b] - base, CAP);
  if (tid < 512) nh[tid] = 0;
  __syncthreads();
  for (int i = tid; i < count; i += 1024) atomicAdd(&nh[tmp[base + i] & BMASK], 1);
  __syncthreads();
  int d = 0;
  if (tid < 512) { d = nh[tid]; sc[tid] = d; }
  __syncthreads();
  for (int off = 1; off < 512; off <<= 1) {
    int a = 0;
    if (tid < 512) { a = sc[tid]; if (tid >= off) a += sc[tid - off]; }
    __syncthreads();
    if (tid < 512) sc[tid] = a;
    __syncthreads();
  }
  if (tid < 512) {
    int e0 = base + sc[tid] - d;  // exclusive prefix
    lcur[tid] = e0;
    int v = (b << BSHIFT) + tid;
    if (v < n) {
      row_start[v] = e0; degs[v] = d;
      dinv[v] = rsqrtf((float)(d + 1));
    }
  }
  __syncthreads();
  for (int i = tid; i < count; i += 1024) {
    int val = tmp[base + i];
    int pos = atomicAdd(&lcur[val & BMASK], 1);
    csr[pos] = val >> BSHIFT;
  }
}

// h1s[row] = bf16x2-packed dinv[row] * (x[row] @ W1), via MFMA (R9-proven).
__global__ __launch_bounds__(256, 4) void gemm1_kernel(const float* __restrict__ x,
                                                       const float* __restrict__ W1,
                                                       const float* __restrict__ dinv,
                                                       unsigned* __restrict__ h1s, int n) {
  __shared__ unsigned lds_u[64 * 68 * 2];
  unsigned* xs = lds_u;
  unsigned* wt = lds_u + 64 * 68;
  int tid = threadIdx.x;
  int vb = blockIdx.x * 64;
  int nrows = min(64, n - vb);

  // stage x: coalesced float4 loads, pack to bf16x2
  const float4* xg = (const float4*)(x + (size_t)vb * 128);
#pragma unroll
  for (int it = 0; it < 8; ++it) {
    int idx = it * 256 + tid;
    int r = idx >> 5, c2 = idx & 31;
    float4 vv = make_float4(0.f, 0.f, 0.f, 0.f);
    if (r < nrows) vv = xg[idx];
    xs[r * 68 + c2 * 2] = (f2b(vv.y) << 16) | f2b(vv.x);
    xs[r * 68 + c2 * 2 + 1] = (f2b(vv.w) << 16) | f2b(vv.z);
  }
  // stage W1^T: wt16[n][k] bf16, stride 136 u16 (= 68 u32)
  unsigned short* wt16 = (unsigned short*)wt;
  const float4* wg = (const float4*)W1;
#pragma unroll
  for (int it = 0; it < 8; ++it) {
    int idx = it * 256 + tid;          // [0,2048): k = idx>>4, n0 = (idx&15)*4
    int k = idx >> 4, n0 = (idx & 15) * 4;
    float4 wv = wg[idx];
    wt16[(n0 + 0) * 136 + k] = (unsigned short)f2b(wv.x);
    wt16[(n0 + 1) * 136 + k] = (unsigned short)f2b(wv.y);
    wt16[(n0 + 2) * 136 + k] = (unsigned short)f2b(wv.z);
    wt16[(n0 + 3) * 136 + k] = (unsigned short)f2b(wv.w);
  }
  __syncthreads();

  int lane = tid & 63, wid = tid >> 6;
  int m16 = lane & 15, quad = lane >> 4;
  const unsigned* xp = xs + (wid * 16 + m16) * 68 + quad * 4;
  const unsigned* wp = wt + m16 * 68 + quad * 4;
  f32x4 acc[4] = {};
#pragma unroll
  for (int ks = 0; ks < 4; ++ks) {
    bf16x8 a = *(const bf16x8*)(xp + ks * 16);
#pragma unroll
    for (int nt = 0; nt < 4; ++nt) {
      bf16x8 b = *(const bf16x8*)(wp + nt * 16 * 68 + ks * 16);
      acc[nt] = __builtin_amdgcn_mfma_f32_16x16x32_bf16(a, b, acc[nt], 0, 0, 0);
    }
  }
  // epilogue: C[row = quad*4+reg][col = nt*16+m16]; fold dinv, pack bf16
  int rbase = vb + wid * 16 + quad * 4;
  float dvv[4];
#pragma unroll
  for (int reg = 0; reg < 4; ++reg) {
    int row = rbase + reg;
    dvv[reg] = (row < n) ? dinv[row] : 0.f;
  }
  unsigned short* h16 = (unsigned short*)h1s;
#pragma unroll
  for (int nt = 0; nt < 4; ++nt) {
    int col = nt * 16 + m16;
#pragma unroll
    for (int reg = 0; reg < 4; ++reg) {
      int row = rbase + reg;
      if (row < n)
        h16[(size_t)row * 64 + col] = (unsigned short)f2b(dvv[reg] * acc[nt][reg]);
    }
  }
}

struct f2 { float x, y; };
__device__ __forceinline__ void addu(f2& a, unsigned u) {
  a.x += __uint_as_float(u << 16);
  a.y += __uint_as_float(u);  // low 16 bits are mantissa noise (<=0.4% rel)
}
__device__ __forceinline__ void addu4(f2* a, uint4 g) {
  addu(a[0], g.x); addu(a[1], g.y); addu(a[2], g.z); addu(a[3], g.w);
}

// Half-wave per node (R10-proven): lanes 0-31 node A, 32-63 node B.
// sub=lane&31: e=sub>>3 in [0,4), c=sub&7. 2 uint4 gathers/iter = 8 edges/node.
// Row n of h1s is zeros -> masked tails branch-free. Grid-stride, 8 nodes/blk.
__global__ __launch_bounds__(256) void agg1_kernel(const uint4* __restrict__ h1s4,
                                                   const float* __restrict__ dinv,
                                                   const int* __restrict__ row_start,
                                                   const int* __restrict__ degs,
                                                   const int* __restrict__ csr,
                                                   const float* __restrict__ b1,
                                                   const float* __restrict__ W2,
                                                   unsigned* __restrict__ t, int n) {
  __shared__ float W2s[64 * 17];
  __shared__ float b1s[64];
  __shared__ float a_s[4][2][64];
  for (int i = threadIdx.x; i < 1024; i += 256)
    W2s[(i >> 4) * 17 + (i & 15)] = W2[i];
  if (threadIdx.x < 64) b1s[threadIdx.x] = b1[threadIdx.x];
  // zero t row n for agg2's masked gathers (tmp alias is dead by now)
  if (blockIdx.x == 0 && threadIdx.x < 8) t[(size_t)n * 8 + threadIdx.x] = 0u;
  __syncthreads();

  int wave = threadIdx.x >> 6, lane = threadIdx.x & 63;
  int half = lane >> 5, sub = lane & 31;
  int e = sub >> 3, c = sub & 7;
  int j = sub & 15, grp = (sub >> 4) & 1;

  for (int vbase = blockIdx.x * 8; vbase < n; vbase += gridDim.x * 8) {
    int v = vbase + wave * 2 + half;
    bool valid = (v < n);            // half-uniform
    int vc = valid ? v : 0;
    int i = row_start[vc];
    int e1 = i + (valid ? degs[vc] : 0);
    float dv = valid ? dinv[vc] : 0.f;

    f2 a0[4];
#pragma unroll
    for (int k = 0; k < 4; ++k) a0[k] = {0.f, 0.f};
    {  // self loop: e==0 lanes pull row v (c=sub), others pull zero row
      int s = (valid && sub < 8) ? v : n;
      addu4(a0, h1s4[(size_t)s * 8 + c]);
    }
    while (__any(i < e1)) {
      int i0 = i + e, i1 = i + 4 + e;
      int s0v = csr[i0];              // padded/bucket-gap reads are safe
      int s1v = csr[i1];
      int s0 = (i0 < e1) ? s0v : n;
      int s1 = (i1 < e1) ? s1v : n;
      uint4 g0 = h1s4[(size_t)s0 * 8 + c];
      uint4 g1 = h1s4[(size_t)s1 * 8 + c];
      addu4(a0, g0);
      addu4(a0, g1);
      i += 8;
    }
    // reduce across e (lane bits 3,4 within half): 2 levels
#pragma unroll
    for (int m = 8; m <= 16; m <<= 1) {
#pragma unroll
      for (int k = 0; k < 4; ++k) {
        a0[k].x += __shfl_xor(a0[k].x, m, 64);
        a0[k].y += __shfl_xor(a0[k].y, m, 64);
      }
    }
    if (sub < 8) {  // e==0; c==sub; features 8c..8c+7
#pragma unroll
      for (int k = 0; k < 4; ++k) {
        float z0 = fmaf(dv, a0[k].x, b1s[8 * sub + 2 * k]);
        float z1 = fmaf(dv, a0[k].y, b1s[8 * sub + 2 * k + 1]);
        a_s[wave][half][8 * sub + 2 * k] = fmaxf(z0, 0.2f * z0);
        a_s[wave][half][8 * sub + 2 * k + 1] = fmaxf(z1, 0.2f * z1);
      }
    }
    // MLP 64->16: each half-lane sums 32 features (grp*16 and 32+grp*16)
    float p = 0.f;
#pragma unroll
    for (int q = 0; q < 16; ++q) {
      int f = grp * 16 + q;
      p = fmaf(a_s[wave][half][f], W2s[f * 17 + j], p);
    }
#pragma unroll
    for (int q = 0; q < 16; ++q) {
      int f = 32 + grp * 16 + q;
      p = fmaf(a_s[wave][half][f], W2s[f * 17 + j], p);
    }
    p += __shfl_xor(p, 16, 64);  // combine grp halves (lane bit 4)
    // pack pairs: sub<16 holds feature j; even subs write u32 (j, j+1)
    float pv = dv * p;
    float po = __shfl_xor(pv, 1, 64);
    if (valid && sub < 16 && !(sub & 1))
      t[(size_t)v * 8 + (sub >> 1)] = (f2b(po) << 16) | f2b(pv);
  }
}

// 16 lanes per node, bf16 t rows (32B). sub=lane&15: e=sub>>1 (8 edge slots),
// c=sub&1 (uint4 half = features 8c..8c+7). One wave-load = 8 edges x 4 nodes.
// Row n of t is zeros. log_softmax via 8-local + xor-1 lane reduce.
__global__ __launch_bounds__(256) void agg2_kernel(const uint4* __restrict__ t4,
                                                   const float* __restrict__ dinv,
                                                   const int* __restrict__ row_start,
                                                   const int* __restrict__ degs,
                                                   const int* __restrict__ csr,
                                                   const float* __restrict__ b2,
                                                   float* __restrict__ out, int n) {
  int idx = blockIdx.x * 256 + threadIdx.x;
  int v = idx >> 4;
  if (v >= n) return;
  int sub = threadIdx.x & 15;
  int e = sub >> 1, c = sub & 1;
  float dv = dinv[v];
  int e0 = row_start[v], e1 = e0 + degs[v];
  f2 A0[4], A1[4];
#pragma unroll
  for (int k = 0; k < 4; ++k) { A0[k] = {0.f, 0.f}; A1[k] = {0.f, 0.f}; }
  {  // self loop
    int s = (e == 0) ? v : n;
    addu4(A0, t4[(size_t)s * 2 + c]);
  }
  int i = e0;
  while (i + 8 < e1) {
    int i1 = i + 8 + e;
    int s0 = csr[i + e];
    int s1v = csr[i1];
    int s1 = (i1 < e1) ? s1v : n;
    uint4 g0 = t4[(size_t)s0 * 2 + c];
    uint4 g1 = t4[(size_t)s1 * 2 + c];
    addu4(A0, g0);
    addu4(A1, g1);
    i += 16;
  }
  if (i < e1) {
    int i0 = i + e;
    int sv = csr[i0];
    int s = (i0 < e1) ? sv : n;
    addu4(A0, t4[(size_t)s * 2 + c]);
  }
#pragma unroll
  for (int k = 0; k < 4; ++k) { A0[k].x += A1[k].x; A0[k].y += A1[k].y; }
#pragma unroll
  for (int m = 2; m <= 8; m <<= 1) {  // reduce across e-groups (sub bits 1..3)
#pragma unroll
    for (int k = 0; k < 4; ++k) {
      A0[k].x += __shfl_xor(A0[k].x, m, 64);
      A0[k].y += __shfl_xor(A0[k].y, m, 64);
    }
  }
  // z for features 8c..8c+7
  float4 bb0 = ((const float4*)b2)[c * 2];
  float4 bb1 = ((const float4*)b2)[c * 2 + 1];
  float z[8];
  z[0] = fmaf(dv, A0[0].x, bb0.x); z[1] = fmaf(dv, A0[0].y, bb0.y);
  z[2] = fmaf(dv, A0[1].x, bb0.z); z[3] = fmaf(dv, A0[1].y, bb0.w);
  z[4] = fmaf(dv, A0[2].x, bb1.x); z[5] = fmaf(dv, A0[2].y, bb1.y);
  z[6] = fmaf(dv, A0[3].x, bb1.z); z[7] = fmaf(dv, A0[3].y, bb1.w);
  float mx = z[0];
#pragma unroll
  for (int q = 1; q < 8; ++q) mx = fmaxf(mx, z[q]);
  mx = fmaxf(mx, __shfl_xor(mx, 1, 64));  // combine c halves
  float ss = 0.f;
#pragma unroll
  for (int q = 0; q < 8; ++q) ss += expf(z[q] - mx);
  ss += __shfl_xor(ss, 1, 64);
  float lg = mx + logf(ss);
  if (e == 0) {
    float4 r0 = make_float4(z[0] - lg, z[1] - lg, z[2] - lg, z[3] - lg);
    float4 r1 = make_float4(z[4] - lg, z[5] - lg, z[6] - lg, z[7] - lg);
    float4* o = (float4*)out + (size_t)v * 4 + c * 2;
    o[0] = r0;
    o[1] = r1;
  }
}

extern "C" void kernel_launch(void* const* d_in, const int* in_sizes, int n_in,
                              void* d_out, int out_size, void* d_ws, size_t ws_size,
                              hipStream_t stream) {
  const float* x = (const float*)d_in[0];
  const int* edge_index = (const int*)d_in[1];
  const float* W1 = (const float*)d_in[2];
  const float* b1 = (const float*)d_in[3];
  const float* W2 = (const float*)d_in[4];
  const float* b2 = (const float*)d_in[5];
  float* out = (float*)d_out;

  int N_ = in_sizes[0] / 128;
  int E_ = in_sizes[1] / 2;
  const int* src = edge_index;
  const int* dst = edge_index + E_;
  int NBc = (N_ + BMASK) >> BSHIFT;  // 196 buckets of 512 nodes (<= 256)

  char* ws = (char*)d_ws;
  size_t off = 0;
  auto take = [&](size_t bytes) {
    void* p = ws + off;
    off += (bytes + 255) & ~(size_t)255;
    return p;
  };
  unsigned* h1s = (unsigned*)take(((size_t)N_ + 1) * 32 * 4);  // +1 zero row
  // t ((N+1)*8*4 bf16-packed) aliases tmp (NBc*CAP*4): tmp dead before agg1.
  size_t t_bytes = ((size_t)N_ + 1) * 8 * 4, tmp_bytes = (size_t)NBc * CAP * 4;
  void* t_union = take(t_bytes > tmp_bytes ? t_bytes : tmp_bytes);
  unsigned* t = (unsigned*)t_union;
  int* tmp = (int*)t_union;
  float* dinv = (float*)take((size_t)N_ * 4);
  int* degs = (int*)take((size_t)N_ * 4);
  int* row_start = (int*)take(((size_t)N_ + 1) * 4);
  int* csr = (int*)take(((size_t)NBc * CAP + 16) * 4);  // bucket-local + pad
  int* gbcursor = (int*)take((size_t)NBc * 4);
  (void)ws_size;

  binit_kernel<<<(NBc + 255) / 256, 256, 0, stream>>>(gbcursor, NBc, h1s, N_);
  scatterA_kernel<<<(E_ + CHUNK - 1) / CHUNK, 256, 0, stream>>>(src, dst, E_, NBc,
                                                                gbcursor, tmp);
  csrbuild_kernel<<<NBc, 1024, 0, stream>>>(tmp, gbcursor, N_, row_start, degs,
                                            dinv, csr);
  gemm1_kernel<<<(N_ + 63) / 64, 256, 0, stream>>>(x, W1, dinv, h1s, N_);
  agg1_kernel<<<2048, 256, 0, stream>>>((const uint4*)h1s, dinv, row_start, degs,
                                        csr, b1, W2, t, N_);
  agg2_kernel<<<(N_ * 16 + 255) / 256, 256, 0, stream>>>((const uint4*)t, dinv,
                                                         row_start, degs, csr,
                                                         b2, out, N_);
}